// Round 2
// baseline (508.492 us; speedup 1.0000x reference)
//
#include <hip/hip_runtime.h>
#include <hip/hip_bf16.h>

#define FEATN 898
#define EMBD 128

// ---------------- layout probe: int32 vs int64(lo,hi) storage of edge_index ----------------
// If buffer is int64 pairs, every odd int32 slot (hi word, ids < 2^16) is 0.
__global__ void k_detect(const int* __restrict__ ei32, int* __restrict__ flag) {
    __shared__ int any;
    int t = threadIdx.x;
    if (t == 0) any = 0;
    __syncthreads();
    if (ei32[2 * t + 1] != 0) atomicOr(&any, 1);
    __syncthreads();
    if (t == 0) flag[0] = any;   // 1 = int32 layout, 0 = int64 layout
}

// ---------------- init: deg=1 (self loop), zero fc1 accumulator ----------------
__global__ void k_init(int* __restrict__ deg, float* __restrict__ accum, int N) {
    int i = blockIdx.x * blockDim.x + threadIdx.x;
    if (i < N) deg[i] = 1;
    if (i < 128) accum[i] = 0.f;
}

// ---------------- histogram of dst ----------------
__global__ void k_hist(const int* __restrict__ ei, int E, int N,
                       const int* __restrict__ flag, int* __restrict__ deg) {
    int e = blockIdx.x * blockDim.x + threadIdx.x;
    if (e < E) {
        int d = flag[0] ? ei[(size_t)E + e] : ei[2 * ((size_t)E + e)];
        d = min(max(d, 0), N - 1);
        atomicAdd(&deg[d], 1);
    }
}

// ---------------- scan part A: per-chunk sums (chunk=256) ----------------
__global__ void k_scanA(const int* __restrict__ deg, int N, int* __restrict__ csum) {
    __shared__ int s[256];
    int i = blockIdx.x * 256 + threadIdx.x;
    int v = (i < N) ? deg[i] : 0;
    s[threadIdx.x] = v;
    __syncthreads();
    for (int o = 128; o > 0; o >>= 1) {
        if (threadIdx.x < o) s[threadIdx.x] += s[threadIdx.x + o];
        __syncthreads();
    }
    if (threadIdx.x == 0) csum[blockIdx.x] = s[0];
}

// ---------------- scan part B: exclusive scan of chunk sums (nc<=256) ----------------
__global__ void k_scanB(const int* __restrict__ csum, int nc, int* __restrict__ coff,
                        int* __restrict__ rowoff, int N) {
    __shared__ int s[256];
    int t = threadIdx.x;
    int v = (t < nc) ? csum[t] : 0;
    s[t] = v;
    __syncthreads();
    for (int o = 1; o < 256; o <<= 1) {
        int x_ = (t >= o) ? s[t - o] : 0;
        __syncthreads();
        s[t] += x_;
        __syncthreads();
    }
    if (t < nc) coff[t] = s[t] - v;      // exclusive
    if (t == 255) rowoff[N] = s[255];    // grand total (= E + N)
}

// ---------------- scan part C: per-element exclusive offsets + cur copy + dinv ----------------
__global__ void k_scanC(const int* __restrict__ deg, int N, const int* __restrict__ coff,
                        int* __restrict__ rowoff, int* __restrict__ cur, float* __restrict__ dinv) {
    __shared__ int s[256];
    int t = threadIdx.x;
    int i = blockIdx.x * 256 + t;
    int v = (i < N) ? deg[i] : 0;
    s[t] = v;
    __syncthreads();
    for (int o = 1; o < 256; o <<= 1) {
        int x_ = (t >= o) ? s[t - o] : 0;
        __syncthreads();
        s[t] += x_;
        __syncthreads();
    }
    if (i < N) {
        int ex = s[t] - v + coff[blockIdx.x];
        rowoff[i] = ex;
        cur[i] = ex;
        dinv[i] = rsqrtf((float)deg[i]);
    }
}

// ---------------- CSR placement: edges + self loops ----------------
__global__ void k_place(const int* __restrict__ ei, int E, int N, int NNZ,
                        const int* __restrict__ flag, int* __restrict__ cur,
                        int* __restrict__ colidx) {
    int e = blockIdx.x * blockDim.x + threadIdx.x;
    int f = flag[0];
    if (e < E) {
        int sidx = f ? ei[e] : ei[2 * (size_t)e];
        int d = f ? ei[(size_t)E + e] : ei[2 * ((size_t)E + e)];
        sidx = min(max(sidx, 0), N - 1);
        d = min(max(d, 0), N - 1);
        int p = atomicAdd(&cur[d], 1);
        if (p < NNZ) colidx[p] = sidx;
    } else if (e < E + N) {
        int v = e - E;
        int p = atomicAdd(&cur[v], 1);
        if (p < NNZ) colidx[p] = v;
    }
}

// ---------------- injected scalar per row: emb_table[poi[i>>7]][i&127] ----------------
// masked_scatter with K=1 true col (col 0): feat[i][0] = emb[poi[i>>7]][i&127]
__global__ void k_val(const float* __restrict__ x, const float* __restrict__ emb,
                      int N, float* __restrict__ valv) {
    int i = blockIdx.x * blockDim.x + threadIdx.x;
    if (i < N) {
        int r = i >> 7;
        int poi = (int)x[(size_t)r * FEATN];   // POI id stored at column 0
        poi = min(max(poi, 0), N - 1);
        valv[i] = emb[(size_t)poi * EMBD + (i & 127)];
    }
}

// ---------------- GEMM1: out[i][o] = dinv[i]*(x_row . W1[:,o] + corr), 64 cols ----------------
// 32 rows x 64 cols per block; 256 threads; thread = (row lr=tid>>3, col group cg=tid&7, 8 cols)
__global__ __launch_bounds__(256) void k_gemm1(const float* __restrict__ x, const float* __restrict__ W1,
                                               const float* __restrict__ valv,
                                               const float* __restrict__ dinv, int N,
                                               float* __restrict__ out) {
    __shared__ float xs[32][65];
    __shared__ float ws[64][68];
    int tid = threadIdx.x;
    int lr = tid >> 3;
    int cg = tid & 7;
    int r0 = blockIdx.x * 32;
    int row = r0 + lr;

    float acc[8];
#pragma unroll
    for (int j = 0; j < 8; ++j) acc[j] = 0.f;

    for (int k0 = 0; k0 < FEATN; k0 += 64) {
        // load W tile [64][64]
        {
            int kw = tid >> 2;
            int c4 = (tid & 3) * 16;
            int kk = k0 + kw;
#pragma unroll
            for (int j = 0; j < 16; j += 4) {
                float4 wv = make_float4(0.f, 0.f, 0.f, 0.f);
                if (kk < FEATN) wv = *(const float4*)&W1[(size_t)kk * 64 + c4 + j];
                *(float4*)&ws[kw][c4 + j] = wv;
            }
        }
        // load x tile [32][64] via float2 (row byte offsets are 8B aligned: 898*4 % 8 == 0)
        {
            int rr = r0 + lr;
#pragma unroll
            for (int jj = 0; jj < 4; ++jj) {
                int kk = k0 + cg * 8 + 2 * jj;
                float2 xv = make_float2(0.f, 0.f);
                if (rr < N && kk < FEATN) xv = *(const float2*)&x[(size_t)rr * FEATN + kk];
                xs[lr][cg * 8 + 2 * jj]     = xv.x;
                xs[lr][cg * 8 + 2 * jj + 1] = xv.y;
            }
        }
        __syncthreads();
#pragma unroll 4
        for (int kk = 0; kk < 64; ++kk) {
            float xv = xs[lr][kk];
            float4 w0 = *(float4*)&ws[kk][cg * 8];
            float4 w1 = *(float4*)&ws[kk][cg * 8 + 4];
            acc[0] += xv * w0.x; acc[1] += xv * w0.y; acc[2] += xv * w0.z; acc[3] += xv * w0.w;
            acc[4] += xv * w1.x; acc[5] += xv * w1.y; acc[6] += xv * w1.z; acc[7] += xv * w1.w;
        }
        __syncthreads();
    }

    if (row < N) {
        // feat differs from x only at column 0: corr = injected - original
        float corr = valv[row] - x[(size_t)row * FEATN];
        float dv = dinv[row];
        float o8[8];
#pragma unroll
        for (int j = 0; j < 8; ++j) {
            int col = cg * 8 + j;
            o8[j] = dv * (acc[j] + corr * W1[col]);   // W1 row 0
        }
        *(float4*)&out[(size_t)row * 64 + cg * 8]     = make_float4(o8[0], o8[1], o8[2], o8[3]);
        *(float4*)&out[(size_t)row * 64 + cg * 8 + 4] = make_float4(o8[4], o8[5], o8[6], o8[7]);
    }
}

// ---------------- aggregation, 64 features: wave per node ----------------
template <int EPI>  // 0: leaky ; 1: leaky(t)+t
__global__ __launch_bounds__(256) void k_agg64(const float* __restrict__ hw, const int* __restrict__ rowoff,
                                               const int* __restrict__ colidx, const float* __restrict__ dinv,
                                               const float* __restrict__ bias, int N, float* __restrict__ out) {
    int w = threadIdx.x >> 6;
    int lane = threadIdx.x & 63;
    int v = blockIdx.x * 4 + w;
    if (v >= N) return;
    int beg = rowoff[v], end = rowoff[v + 1];
    float a0 = 0.f, a1 = 0.f, a2 = 0.f, a3 = 0.f;
    int i = beg;
    for (; i + 4 <= end; i += 4) {
        int u0 = colidx[i], u1 = colidx[i + 1], u2 = colidx[i + 2], u3 = colidx[i + 3];
        a0 += hw[(size_t)u0 * 64 + lane];
        a1 += hw[(size_t)u1 * 64 + lane];
        a2 += hw[(size_t)u2 * 64 + lane];
        a3 += hw[(size_t)u3 * 64 + lane];
    }
    for (; i < end; ++i) a0 += hw[(size_t)colidx[i] * 64 + lane];
    float t_ = dinv[v] * ((a0 + a1) + (a2 + a3)) + bias[lane];
    float r = (EPI == 0) ? (t_ >= 0.f ? t_ : 0.01f * t_) : (t_ >= 0.f ? 2.f * t_ : 1.01f * t_);
    out[(size_t)v * 64 + lane] = r;
}

// ---------------- aggregation, 32 features: half-wave per node ----------------
template <int EPI>
__global__ __launch_bounds__(256) void k_agg32(const float* __restrict__ hw, const int* __restrict__ rowoff,
                                               const int* __restrict__ colidx, const float* __restrict__ dinv,
                                               const float* __restrict__ bias, int N, float* __restrict__ out) {
    int sub = threadIdx.x >> 5;
    int lane = threadIdx.x & 31;
    int v = blockIdx.x * 8 + sub;
    if (v >= N) return;
    int beg = rowoff[v], end = rowoff[v + 1];
    float a0 = 0.f, a1 = 0.f, a2 = 0.f, a3 = 0.f;
    int i = beg;
    for (; i + 4 <= end; i += 4) {
        int u0 = colidx[i], u1 = colidx[i + 1], u2 = colidx[i + 2], u3 = colidx[i + 3];
        a0 += hw[(size_t)u0 * 32 + lane];
        a1 += hw[(size_t)u1 * 32 + lane];
        a2 += hw[(size_t)u2 * 32 + lane];
        a3 += hw[(size_t)u3 * 32 + lane];
    }
    for (; i < end; ++i) a0 += hw[(size_t)colidx[i] * 32 + lane];
    float t_ = dinv[v] * ((a0 + a1) + (a2 + a3)) + bias[lane];
    float r = (EPI == 0) ? (t_ >= 0.f ? t_ : 0.01f * t_) : (t_ >= 0.f ? 2.f * t_ : 1.01f * t_);
    out[(size_t)v * 32 + lane] = r;
}

// ---------------- small GEMM: out[i][c] = dinv[i] * sum_k h[i][k]*W[k][c] ----------------
template <int K, int C>
__global__ __launch_bounds__(256) void k_gemmS(const float* __restrict__ h, const float* __restrict__ W,
                                               const float* __restrict__ dinv, int N, float* __restrict__ out) {
    __shared__ float ws[K * C];
    for (int j = threadIdx.x; j < K * C; j += 256) ws[j] = W[j];
    __syncthreads();
    const int rpb = 256 / C;
    int lr = threadIdx.x / C;
    int col = threadIdx.x % C;
    int row = blockIdx.x * rpb + lr;
    if (row >= N) return;
    const float* hr = h + (size_t)row * K;
    float acc = 0.f;
#pragma unroll
    for (int k = 0; k < K; ++k) acc += hr[k] * ws[k * C + col];
    out[(size_t)row * C + col] = acc * dinv[row];
}

// ---------------- GEMM5: out[i] = dinv[i] * sum_k h[i][k]*W5[k]  (K=32,C=1) ----------------
__global__ __launch_bounds__(256) void k_gemm5(const float* __restrict__ h, const float* __restrict__ W5,
                                               const float* __restrict__ dinv, int N, float* __restrict__ out) {
    int sub = threadIdx.x >> 5;
    int lane = threadIdx.x & 31;
    int row = blockIdx.x * 8 + sub;
    if (row >= N) return;
    float p = h[(size_t)row * 32 + lane] * W5[lane];
#pragma unroll
    for (int o = 16; o > 0; o >>= 1) p += __shfl_down(p, o, 32);
    if (lane == 0) out[row] = p * dinv[row];
}

// ---------------- aggregation, 1 feature: thread per node ----------------
__global__ void k_agg1f(const float* __restrict__ hw, const int* __restrict__ rowoff,
                        const int* __restrict__ colidx, const float* __restrict__ dinv,
                        const float* __restrict__ b5, int N, float* __restrict__ vvec) {
    int v = blockIdx.x * blockDim.x + threadIdx.x;
    if (v >= N) return;
    int beg = rowoff[v], end = rowoff[v + 1];
    float s = 0.f;
    for (int i = beg; i < end; ++i) s += hw[colidx[i]];
    float h = dinv[v] * s + b5[0];
    vvec[v] = h >= 0.f ? h : 0.01f * h;
}

// ---------------- fc1 partial: accum[o] += sum_r v[r]*fc1W[r][o] ----------------
__global__ __launch_bounds__(128) void k_fc1(const float* __restrict__ vvec, const float* __restrict__ fc1W,
                                             int N, float* __restrict__ accum) {
    int o = threadIdx.x;  // 128
    int rpb = (N + gridDim.x - 1) / gridDim.x;
    int r0 = blockIdx.x * rpb;
    int r1 = r0 + rpb;
    if (r1 > N) r1 = N;
    float acc = 0.f;
    for (int r = r0; r < r1; ++r) acc += vvec[r] * fc1W[(size_t)r * 128 + o];
    atomicAdd(&accum[o], acc);
}

// ---------------- fc2 final ----------------
__global__ __launch_bounds__(128) void k_fc2(const float* __restrict__ accum, const float* __restrict__ fc1b,
                                             const float* __restrict__ fc2W, const float* __restrict__ fc2b,
                                             float* __restrict__ outp) {
    __shared__ float s1[128];
    int t = threadIdx.x;
    float h = accum[t] + fc1b[t];
    s1[t] = h > 0.f ? h : 0.f;
    __syncthreads();
    float acc = fc2b[t];
    for (int o = 0; o < 128; ++o) acc += s1[o] * fc2W[o * 128 + t];
    outp[t] = acc > 0.f ? acc : 0.f;
}

extern "C" void kernel_launch(void* const* d_in, const int* in_sizes, int n_in,
                              void* d_out, int out_size, void* d_ws, size_t ws_size,
                              hipStream_t stream) {
    const float* x = (const float*)d_in[0];
    const int* ei = (const int*)d_in[2];          // int32 (or int64 lo/hi pairs, probed)
    const float* emb = (const float*)d_in[3];
    const float* W1 = (const float*)d_in[4];
    const float* b1 = (const float*)d_in[5];
    const float* W2 = (const float*)d_in[6];
    const float* b2 = (const float*)d_in[7];
    const float* W3 = (const float*)d_in[8];
    const float* b3 = (const float*)d_in[9];
    const float* W4 = (const float*)d_in[10];
    const float* b4 = (const float*)d_in[11];
    const float* W5 = (const float*)d_in[12];
    const float* b5 = (const float*)d_in[13];
    const float* fc1W = (const float*)d_in[14];
    const float* fc1b = (const float*)d_in[15];
    const float* fc2W = (const float*)d_in[16];
    const float* fc2b = (const float*)d_in[17];

    int N = in_sizes[0] / FEATN;
    int E = in_sizes[2] / 2;
    int NNZ = E + N;

    char* w = (char*)d_ws;
    auto alloc = [&](size_t bytes) {
        char* p = w;
        w += (bytes + 255) & ~(size_t)255;
        return p;
    };
    int*   deg    = (int*)alloc((size_t)N * 4);
    float* dinv   = (float*)alloc((size_t)N * 4);
    int*   rowoff = (int*)alloc((size_t)(N + 1) * 4);
    int*   cur    = (int*)alloc((size_t)N * 4);
    int*   colidx = (int*)alloc((size_t)NNZ * 4);
    float* valv   = (float*)alloc((size_t)N * 4);
    int*   csum   = (int*)alloc(1024);
    int*   coff   = (int*)alloc(1024);
    float* accum  = (float*)alloc(512);
    int*   flag   = (int*)alloc(256);
    float* bufA   = (float*)alloc((size_t)N * 64 * 4);
    float* bufB   = (float*)alloc((size_t)N * 64 * 4);
    float* vvec   = (float*)alloc((size_t)N * 4);

    int nb = (N + 255) / 256;

    k_detect<<<1, 256, 0, stream>>>(ei, flag);
    k_init<<<nb, 256, 0, stream>>>(deg, accum, N);
    k_hist<<<(E + 255) / 256, 256, 0, stream>>>(ei, E, N, flag, deg);
    k_scanA<<<nb, 256, 0, stream>>>(deg, N, csum);
    k_scanB<<<1, 256, 0, stream>>>(csum, nb, coff, rowoff, N);
    k_scanC<<<nb, 256, 0, stream>>>(deg, N, coff, rowoff, cur, dinv);
    k_place<<<(E + N + 255) / 256, 256, 0, stream>>>(ei, E, N, NNZ, flag, cur, colidx);
    k_val<<<nb, 256, 0, stream>>>(x, emb, N, valv);

    k_gemm1<<<(N + 31) / 32, 256, 0, stream>>>(x, W1, valv, dinv, N, bufA);
    k_agg64<0><<<(N + 3) / 4, 256, 0, stream>>>(bufA, rowoff, colidx, dinv, b1, N, bufB);

    k_gemmS<64, 32><<<(N + 7) / 8, 256, 0, stream>>>(bufB, W2, dinv, N, bufA);
    k_agg32<0><<<(N + 7) / 8, 256, 0, stream>>>(bufA, rowoff, colidx, dinv, b2, N, bufB);

    k_gemmS<32, 32><<<(N + 7) / 8, 256, 0, stream>>>(bufB, W3, dinv, N, bufA);
    k_agg32<1><<<(N + 7) / 8, 256, 0, stream>>>(bufA, rowoff, colidx, dinv, b3, N, bufB);

    k_gemmS<32, 32><<<(N + 7) / 8, 256, 0, stream>>>(bufB, W4, dinv, N, bufA);
    k_agg32<1><<<(N + 7) / 8, 256, 0, stream>>>(bufA, rowoff, colidx, dinv, b4, N, bufB);

    k_gemm5<<<(N + 7) / 8, 256, 0, stream>>>(bufB, W5, dinv, N, bufA);
    k_agg1f<<<nb, 256, 0, stream>>>(bufA, rowoff, colidx, dinv, b5, N, vvec);

    k_fc1<<<300, 128, 0, stream>>>(vvec, fc1W, N, accum);
    k_fc2<<<1, 128, 0, stream>>>(accum, fc1b, fc2W, fc2b, (float*)d_out);
}

// Round 3
// 420.499 us; speedup vs baseline: 1.2093x; 1.2093x over previous
//
#include <hip/hip_runtime.h>
#include <hip/hip_bf16.h>

#define FEATN 898
#define EMBD 128
#define KT_FULL 28          // 28 full k-tiles of 32 (896), tail handles k=896..897
#define KT_ALL 29           // padded tiles in Wfrag

typedef __bf16 bf16x8 __attribute__((ext_vector_type(8)));
typedef float f32x4 __attribute__((ext_vector_type(4)));
typedef unsigned short ushort8 __attribute__((ext_vector_type(8)));

__device__ inline unsigned short f2bf(float f) {
    unsigned int u = __float_as_uint(f);
    unsigned int r = u + 0x7fffu + ((u >> 16) & 1u);   // RNE
    return (unsigned short)(r >> 16);
}
__device__ inline bf16x8 as_bf16x8(ushort8 u) {
    bf16x8 r;
    __builtin_memcpy(&r, &u, 16);
    return r;
}

// ---------------- layout probe: int32 vs int64(lo,hi) storage of edge_index ----------------
__global__ void k_detect(const int* __restrict__ ei32, int* __restrict__ flag) {
    __shared__ int any;
    int t = threadIdx.x;
    if (t == 0) any = 0;
    __syncthreads();
    if (ei32[2 * t + 1] != 0) atomicOr(&any, 1);
    __syncthreads();
    if (t == 0) flag[0] = any;   // 1 = int32 layout, 0 = int64 layout
}

// ---------------- init: deg=1 (self loop), zero fc1 accumulator ----------------
__global__ void k_init(int* __restrict__ deg, float* __restrict__ accum, int N) {
    int i = blockIdx.x * blockDim.x + threadIdx.x;
    if (i < N) deg[i] = 1;
    if (i < 128) accum[i] = 0.f;
}

// ---------------- histogram of dst ----------------
__global__ void k_hist(const int* __restrict__ ei, int E, int N,
                       const int* __restrict__ flag, int* __restrict__ deg) {
    int e = blockIdx.x * blockDim.x + threadIdx.x;
    if (e < E) {
        int d = flag[0] ? ei[(size_t)E + e] : ei[2 * ((size_t)E + e)];
        d = min(max(d, 0), N - 1);
        atomicAdd(&deg[d], 1);
    }
}

// ---------------- scan part A ----------------
__global__ void k_scanA(const int* __restrict__ deg, int N, int* __restrict__ csum) {
    __shared__ int s[256];
    int i = blockIdx.x * 256 + threadIdx.x;
    int v = (i < N) ? deg[i] : 0;
    s[threadIdx.x] = v;
    __syncthreads();
    for (int o = 128; o > 0; o >>= 1) {
        if (threadIdx.x < o) s[threadIdx.x] += s[threadIdx.x + o];
        __syncthreads();
    }
    if (threadIdx.x == 0) csum[blockIdx.x] = s[0];
}

// ---------------- scan part B ----------------
__global__ void k_scanB(const int* __restrict__ csum, int nc, int* __restrict__ coff,
                        int* __restrict__ rowoff, int N) {
    __shared__ int s[256];
    int t = threadIdx.x;
    int v = (t < nc) ? csum[t] : 0;
    s[t] = v;
    __syncthreads();
    for (int o = 1; o < 256; o <<= 1) {
        int x_ = (t >= o) ? s[t - o] : 0;
        __syncthreads();
        s[t] += x_;
        __syncthreads();
    }
    if (t < nc) coff[t] = s[t] - v;
    if (t == 255) rowoff[N] = s[255];
}

// ---------------- scan part C ----------------
__global__ void k_scanC(const int* __restrict__ deg, int N, const int* __restrict__ coff,
                        int* __restrict__ rowoff, int* __restrict__ cur, float* __restrict__ dinv) {
    __shared__ int s[256];
    int t = threadIdx.x;
    int i = blockIdx.x * 256 + t;
    int v = (i < N) ? deg[i] : 0;
    s[t] = v;
    __syncthreads();
    for (int o = 1; o < 256; o <<= 1) {
        int x_ = (t >= o) ? s[t - o] : 0;
        __syncthreads();
        s[t] += x_;
        __syncthreads();
    }
    if (i < N) {
        int ex = s[t] - v + coff[blockIdx.x];
        rowoff[i] = ex;
        cur[i] = ex;
        dinv[i] = rsqrtf((float)deg[i]);
    }
}

// ---------------- CSR placement ----------------
__global__ void k_place(const int* __restrict__ ei, int E, int N, int NNZ,
                        const int* __restrict__ flag, int* __restrict__ cur,
                        int* __restrict__ colidx) {
    int e = blockIdx.x * blockDim.x + threadIdx.x;
    int f = flag[0];
    if (e < E) {
        int sidx = f ? ei[e] : ei[2 * (size_t)e];
        int d = f ? ei[(size_t)E + e] : ei[2 * ((size_t)E + e)];
        sidx = min(max(sidx, 0), N - 1);
        d = min(max(d, 0), N - 1);
        int p = atomicAdd(&cur[d], 1);
        if (p < NNZ) colidx[p] = sidx;
    } else if (e < E + N) {
        int v = e - E;
        int p = atomicAdd(&cur[v], 1);
        if (p < NNZ) colidx[p] = v;
    }
}

// ---------------- injected scalar: feat[i][0] = emb[poi[i>>7]][i&127] ----------------
__global__ void k_val(const float* __restrict__ x, const float* __restrict__ emb,
                      int N, float* __restrict__ valv) {
    int i = blockIdx.x * blockDim.x + threadIdx.x;
    if (i < N) {
        int r = i >> 7;
        int poi = (int)x[(size_t)r * FEATN];
        poi = min(max(poi, 0), N - 1);
        valv[i] = emb[(size_t)poi * EMBD + (i & 127)];
    }
}

// ---------------- Wfrag prep: W1[898][64] f32 -> fragment-order bf16, zero-padded ----------------
// layout: Wf[((kt*4 + nt)*64 + lane)*8 + e], k = kt*32 + (lane>>4)*8 + e, n = nt*16 + (lane&15)
__global__ void k_prepW(const float* __restrict__ W1, unsigned short* __restrict__ Wf) {
    int id = blockIdx.x * 256 + threadIdx.x;
    if (id >= KT_ALL * 4 * 64 * 8) return;
    int e = id & 7;
    int l = (id >> 3) & 63;
    int nt = (id >> 9) & 3;
    int kt = id >> 11;
    int k = kt * 32 + (l >> 4) * 8 + e;
    int n = nt * 16 + (l & 15);
    float v = (k < FEATN) ? W1[(size_t)k * 64 + n] : 0.f;
    Wf[id] = f2bf(v);
}

// ---------------- GEMM1 via MFMA: out[i][o] = dinv[i]*((x@W1)[i][o] with col0 replaced) ----------------
// Block = 4 waves, each wave owns 16 rows x 64 cols. No LDS, no barriers.
__global__ __launch_bounds__(256) void k_gemm1m(const float* __restrict__ x,
                                                const unsigned short* __restrict__ Wf,
                                                const float* __restrict__ W1,
                                                const float* __restrict__ valv,
                                                const float* __restrict__ dinv, int N,
                                                float* __restrict__ out) {
    int w = threadIdx.x >> 6;
    int l = threadIdx.x & 63;
    int r0 = blockIdx.x * 64 + w * 16;
    int rowa = r0 + (l & 15);
    if (rowa >= N) rowa = N - 1;           // clamp for A-loads; stores guarded below
    int kg = l >> 4;                        // k-group 0..3
    const float* xrow = x + (size_t)rowa * FEATN + kg * 8;
    const ushort8* wf = (const ushort8*)Wf;

    f32x4 acc[4];
#pragma unroll
    for (int nt = 0; nt < 4; ++nt) acc[nt] = (f32x4){0.f, 0.f, 0.f, 0.f};

    for (int kt = 0; kt < KT_FULL; ++kt) {
        // A: 8 consecutive floats of this lane's row (8B-aligned -> float2 loads)
        const float* p = xrow + kt * 32;
        float2 q0 = *(const float2*)(p + 0);
        float2 q1 = *(const float2*)(p + 2);
        float2 q2 = *(const float2*)(p + 4);
        float2 q3 = *(const float2*)(p + 6);
        ushort8 u;
        u[0] = f2bf(q0.x); u[1] = f2bf(q0.y);
        u[2] = f2bf(q1.x); u[3] = f2bf(q1.y);
        u[4] = f2bf(q2.x); u[5] = f2bf(q2.y);
        u[6] = f2bf(q3.x); u[7] = f2bf(q3.y);
        if (kt == 0 && kg == 0) u[0] = 0;   // zero the POI-id column; exact corr in epilogue
        bf16x8 a = as_bf16x8(u);
#pragma unroll
        for (int nt = 0; nt < 4; ++nt) {
            bf16x8 b;
            ushort8 ub = wf[(kt * 4 + nt) * 64 + l];
            __builtin_memcpy(&b, &ub, 16);
            acc[nt] = __builtin_amdgcn_mfma_f32_16x16x32_bf16(a, b, acc[nt], 0, 0, 0);
        }
    }
    // tail k-tile (k = 896, 897 only; Wf rows for k>=898 are zero)
    {
        ushort8 u = (ushort8)0;
        if (kg == 0) {
            float2 q = *(const float2*)(x + (size_t)rowa * FEATN + 896);
            u[0] = f2bf(q.x);
            u[1] = f2bf(q.y);
        }
        bf16x8 a = as_bf16x8(u);
#pragma unroll
        for (int nt = 0; nt < 4; ++nt) {
            bf16x8 b;
            ushort8 ub = wf[(KT_FULL * 4 + nt) * 64 + l];
            __builtin_memcpy(&b, &ub, 16);
            acc[nt] = __builtin_amdgcn_mfma_f32_16x16x32_bf16(a, b, acc[nt], 0, 0, 0);
        }
    }

    // epilogue: C/D layout col=lane&15, row=(lane>>4)*4+reg
    int colb = l & 15;
    int rquad = l >> 4;
    float dv[4], vv[4];
    int rowbase = r0 + rquad * 4;
#pragma unroll
    for (int rg = 0; rg < 4; ++rg) {
        int row = rowbase + rg;
        int rc = (row < N) ? row : (N - 1);
        dv[rg] = dinv[rc];
        vv[rg] = valv[rc];
    }
#pragma unroll
    for (int nt = 0; nt < 4; ++nt) {
        int col = nt * 16 + colb;
        float wcol = W1[col];               // W1[0][col]
#pragma unroll
        for (int rg = 0; rg < 4; ++rg) {
            int row = rowbase + rg;
            if (row < N)
                out[(size_t)row * 64 + col] = dv[rg] * (acc[nt][rg] + vv[rg] * wcol);
        }
    }
}

// ---------------- aggregation, 64 features: wave per node ----------------
template <int EPI>  // 0: leaky ; 1: leaky(t)+t
__global__ __launch_bounds__(256) void k_agg64(const float* __restrict__ hw, const int* __restrict__ rowoff,
                                               const int* __restrict__ colidx, const float* __restrict__ dinv,
                                               const float* __restrict__ bias, int N, float* __restrict__ out) {
    int w = threadIdx.x >> 6;
    int lane = threadIdx.x & 63;
    int v = blockIdx.x * 4 + w;
    if (v >= N) return;
    int beg = rowoff[v], end = rowoff[v + 1];
    float a0 = 0.f, a1 = 0.f, a2 = 0.f, a3 = 0.f;
    int i = beg;
    for (; i + 4 <= end; i += 4) {
        int u0 = colidx[i], u1 = colidx[i + 1], u2 = colidx[i + 2], u3 = colidx[i + 3];
        a0 += hw[(size_t)u0 * 64 + lane];
        a1 += hw[(size_t)u1 * 64 + lane];
        a2 += hw[(size_t)u2 * 64 + lane];
        a3 += hw[(size_t)u3 * 64 + lane];
    }
    for (; i < end; ++i) a0 += hw[(size_t)colidx[i] * 64 + lane];
    float t_ = dinv[v] * ((a0 + a1) + (a2 + a3)) + bias[lane];
    float r = (EPI == 0) ? (t_ >= 0.f ? t_ : 0.01f * t_) : (t_ >= 0.f ? 2.f * t_ : 1.01f * t_);
    out[(size_t)v * 64 + lane] = r;
}

// ---------------- aggregation, 32 features: half-wave per node ----------------
template <int EPI>
__global__ __launch_bounds__(256) void k_agg32(const float* __restrict__ hw, const int* __restrict__ rowoff,
                                               const int* __restrict__ colidx, const float* __restrict__ dinv,
                                               const float* __restrict__ bias, int N, float* __restrict__ out) {
    int sub = threadIdx.x >> 5;
    int lane = threadIdx.x & 31;
    int v = blockIdx.x * 8 + sub;
    if (v >= N) return;
    int beg = rowoff[v], end = rowoff[v + 1];
    float a0 = 0.f, a1 = 0.f, a2 = 0.f, a3 = 0.f;
    int i = beg;
    for (; i + 4 <= end; i += 4) {
        int u0 = colidx[i], u1 = colidx[i + 1], u2 = colidx[i + 2], u3 = colidx[i + 3];
        a0 += hw[(size_t)u0 * 32 + lane];
        a1 += hw[(size_t)u1 * 32 + lane];
        a2 += hw[(size_t)u2 * 32 + lane];
        a3 += hw[(size_t)u3 * 32 + lane];
    }
    for (; i < end; ++i) a0 += hw[(size_t)colidx[i] * 32 + lane];
    float t_ = dinv[v] * ((a0 + a1) + (a2 + a3)) + bias[lane];
    float r = (EPI == 0) ? (t_ >= 0.f ? t_ : 0.01f * t_) : (t_ >= 0.f ? 2.f * t_ : 1.01f * t_);
    out[(size_t)v * 32 + lane] = r;
}

// ---------------- small GEMM ----------------
template <int K, int C>
__global__ __launch_bounds__(256) void k_gemmS(const float* __restrict__ h, const float* __restrict__ W,
                                               const float* __restrict__ dinv, int N, float* __restrict__ out) {
    __shared__ float ws[K * C];
    for (int j = threadIdx.x; j < K * C; j += 256) ws[j] = W[j];
    __syncthreads();
    const int rpb = 256 / C;
    int lr = threadIdx.x / C;
    int col = threadIdx.x % C;
    int row = blockIdx.x * rpb + lr;
    if (row >= N) return;
    const float* hr = h + (size_t)row * K;
    float acc = 0.f;
#pragma unroll
    for (int k = 0; k < K; ++k) acc += hr[k] * ws[k * C + col];
    out[(size_t)row * C + col] = acc * dinv[row];
}

// ---------------- GEMM5 ----------------
__global__ __launch_bounds__(256) void k_gemm5(const float* __restrict__ h, const float* __restrict__ W5,
                                               const float* __restrict__ dinv, int N, float* __restrict__ out) {
    int sub = threadIdx.x >> 5;
    int lane = threadIdx.x & 31;
    int row = blockIdx.x * 8 + sub;
    if (row >= N) return;
    float p = h[(size_t)row * 32 + lane] * W5[lane];
#pragma unroll
    for (int o = 16; o > 0; o >>= 1) p += __shfl_down(p, o, 32);
    if (lane == 0) out[row] = p * dinv[row];
}

// ---------------- aggregation, 1 feature ----------------
__global__ void k_agg1f(const float* __restrict__ hw, const int* __restrict__ rowoff,
                        const int* __restrict__ colidx, const float* __restrict__ dinv,
                        const float* __restrict__ b5, int N, float* __restrict__ vvec) {
    int v = blockIdx.x * blockDim.x + threadIdx.x;
    if (v >= N) return;
    int beg = rowoff[v], end = rowoff[v + 1];
    float s = 0.f;
    for (int i = beg; i < end; ++i) s += hw[colidx[i]];
    float h = dinv[v] * s + b5[0];
    vvec[v] = h >= 0.f ? h : 0.01f * h;
}

// ---------------- fc1 partial ----------------
__global__ __launch_bounds__(128) void k_fc1(const float* __restrict__ vvec, const float* __restrict__ fc1W,
                                             int N, float* __restrict__ accum) {
    int o = threadIdx.x;
    int rpb = (N + gridDim.x - 1) / gridDim.x;
    int r0 = blockIdx.x * rpb;
    int r1 = r0 + rpb;
    if (r1 > N) r1 = N;
    float acc = 0.f;
    for (int r = r0; r < r1; ++r) acc += vvec[r] * fc1W[(size_t)r * 128 + o];
    atomicAdd(&accum[o], acc);
}

// ---------------- fc2 final ----------------
__global__ __launch_bounds__(128) void k_fc2(const float* __restrict__ accum, const float* __restrict__ fc1b,
                                             const float* __restrict__ fc2W, const float* __restrict__ fc2b,
                                             float* __restrict__ outp) {
    __shared__ float s1[128];
    int t = threadIdx.x;
    float h = accum[t] + fc1b[t];
    s1[t] = h > 0.f ? h : 0.f;
    __syncthreads();
    float acc = fc2b[t];
    for (int o = 0; o < 128; ++o) acc += s1[o] * fc2W[o * 128 + t];
    outp[t] = acc > 0.f ? acc : 0.f;
}

extern "C" void kernel_launch(void* const* d_in, const int* in_sizes, int n_in,
                              void* d_out, int out_size, void* d_ws, size_t ws_size,
                              hipStream_t stream) {
    const float* x = (const float*)d_in[0];
    const int* ei = (const int*)d_in[2];
    const float* emb = (const float*)d_in[3];
    const float* W1 = (const float*)d_in[4];
    const float* b1 = (const float*)d_in[5];
    const float* W2 = (const float*)d_in[6];
    const float* b2 = (const float*)d_in[7];
    const float* W3 = (const float*)d_in[8];
    const float* b3 = (const float*)d_in[9];
    const float* W4 = (const float*)d_in[10];
    const float* b4 = (const float*)d_in[11];
    const float* W5 = (const float*)d_in[12];
    const float* b5 = (const float*)d_in[13];
    const float* fc1W = (const float*)d_in[14];
    const float* fc1b = (const float*)d_in[15];
    const float* fc2W = (const float*)d_in[16];
    const float* fc2b = (const float*)d_in[17];

    int N = in_sizes[0] / FEATN;
    int E = in_sizes[2] / 2;
    int NNZ = E + N;

    char* w = (char*)d_ws;
    auto alloc = [&](size_t bytes) {
        char* p = w;
        w += (bytes + 255) & ~(size_t)255;
        return p;
    };
    int*   deg    = (int*)alloc((size_t)N * 4);
    float* dinv   = (float*)alloc((size_t)N * 4);
    int*   rowoff = (int*)alloc((size_t)(N + 1) * 4);
    int*   cur    = (int*)alloc((size_t)N * 4);
    int*   colidx = (int*)alloc((size_t)NNZ * 4);
    float* valv   = (float*)alloc((size_t)N * 4);
    int*   csum   = (int*)alloc(1024);
    int*   coff   = (int*)alloc(1024);
    float* accum  = (float*)alloc(512);
    int*   flag   = (int*)alloc(256);
    unsigned short* Wf = (unsigned short*)alloc((size_t)KT_ALL * 4 * 64 * 8 * 2);
    float* bufA   = (float*)alloc((size_t)N * 64 * 4);
    float* bufB   = (float*)alloc((size_t)N * 64 * 4);
    float* vvec   = (float*)alloc((size_t)N * 4);

    int nb = (N + 255) / 256;

    k_detect<<<1, 256, 0, stream>>>(ei, flag);
    k_init<<<nb, 256, 0, stream>>>(deg, accum, N);
    k_hist<<<(E + 255) / 256, 256, 0, stream>>>(ei, E, N, flag, deg);
    k_scanA<<<nb, 256, 0, stream>>>(deg, N, csum);
    k_scanB<<<1, 256, 0, stream>>>(csum, nb, coff, rowoff, N);
    k_scanC<<<nb, 256, 0, stream>>>(deg, N, coff, rowoff, cur, dinv);
    k_place<<<(E + N + 255) / 256, 256, 0, stream>>>(ei, E, N, NNZ, flag, cur, colidx);
    k_val<<<nb, 256, 0, stream>>>(x, emb, N, valv);
    k_prepW<<<(KT_ALL * 4 * 64 * 8 + 255) / 256, 256, 0, stream>>>(W1, Wf);

    k_gemm1m<<<(N + 63) / 64, 256, 0, stream>>>(x, Wf, W1, valv, dinv, N, bufA);
    k_agg64<0><<<(N + 3) / 4, 256, 0, stream>>>(bufA, rowoff, colidx, dinv, b1, N, bufB);

    k_gemmS<64, 32><<<(N + 7) / 8, 256, 0, stream>>>(bufB, W2, dinv, N, bufA);
    k_agg32<0><<<(N + 7) / 8, 256, 0, stream>>>(bufA, rowoff, colidx, dinv, b2, N, bufB);

    k_gemmS<32, 32><<<(N + 7) / 8, 256, 0, stream>>>(bufB, W3, dinv, N, bufA);
    k_agg32<1><<<(N + 7) / 8, 256, 0, stream>>>(bufA, rowoff, colidx, dinv, b3, N, bufB);

    k_gemmS<32, 32><<<(N + 7) / 8, 256, 0, stream>>>(bufB, W4, dinv, N, bufA);
    k_agg32<1><<<(N + 7) / 8, 256, 0, stream>>>(bufA, rowoff, colidx, dinv, b4, N, bufB);

    k_gemm5<<<(N + 7) / 8, 256, 0, stream>>>(bufB, W5, dinv, N, bufA);
    k_agg1f<<<nb, 256, 0, stream>>>(bufA, rowoff, colidx, dinv, b5, N, vvec);

    k_fc1<<<300, 128, 0, stream>>>(vvec, fc1W, N, accum);
    k_fc2<<<1, 128, 0, stream>>>(accum, fc1b, fc2W, fc2b, (float*)d_out);
}

// Round 4
// 377.788 us; speedup vs baseline: 1.3460x; 1.1131x over previous
//
#include <hip/hip_runtime.h>
#include <hip/hip_bf16.h>

#define FEATN 898
#define EMBD 128
#define KT_FULL 28          // 28 full k-tiles of 32 (896), tail handles k=896..897
#define KT_ALL 29           // padded tiles in Wfrag
#define CAPB 512            // per (bucket, slice) capacity; mean ~256, +16 sigma

typedef __bf16 bf16x8 __attribute__((ext_vector_type(8)));
typedef float f32x4 __attribute__((ext_vector_type(4)));
typedef unsigned short ushort8 __attribute__((ext_vector_type(8)));

__device__ inline unsigned short f2bf(float f) {
    unsigned int u = __float_as_uint(f);
    unsigned int r = u + 0x7fffu + ((u >> 16) & 1u);   // RNE
    return (unsigned short)(r >> 16);
}
__device__ inline bf16x8 as_bf16x8(ushort8 u) {
    bf16x8 r;
    __builtin_memcpy(&r, &u, 16);
    return r;
}

// ---------------- layout probe: int32 vs int64(lo,hi) storage of edge_index ----------------
__global__ void k_detect(const int* __restrict__ ei32, int* __restrict__ flag) {
    __shared__ int any;
    int t = threadIdx.x;
    if (t == 0) any = 0;
    __syncthreads();
    if (ei32[2 * t + 1] != 0) atomicOr(&any, 1);
    __syncthreads();
    if (t == 0) flag[0] = any;   // 1 = int32 layout, 0 = int64 layout
}

// ---------------- init: zero bucket tails + fc1 accumulator ----------------
__global__ void k_init(int* __restrict__ tails, int ntails, float* __restrict__ accum, int N) {
    int i = blockIdx.x * blockDim.x + threadIdx.x;
    if (i < ntails) tails[i] = 0;
    if (i < 128) accum[i] = 0.f;
}

// ---------------- pass 1: bucket edges by dst>>6 into per-(bucket,slice) append streams ----------------
// slice = blockIdx&7 ~ XCD under round-robin dispatch -> same-line appends stay XCD/time-local.
__global__ void k_p1(const int* __restrict__ ei, int E, int N, const int* __restrict__ flag,
                     int* __restrict__ tails, unsigned int* __restrict__ bucketBuf) {
    int e = blockIdx.x * 256 + threadIdx.x;
    if (e >= E) return;
    int f = flag[0];
    int s = f ? ei[e] : ei[2 * (size_t)e];
    int d = f ? ei[(size_t)E + e] : ei[2 * ((size_t)E + e)];
    s = min(max(s, 0), N - 1);
    d = min(max(d, 0), N - 1);
    int cell = (d >> 6) * 8 + (blockIdx.x & 7);
    int pos = atomicAdd(&tails[cell], 1);
    if (pos < CAPB) bucketBuf[(size_t)cell * CAPB + pos] = ((unsigned)s << 6) | (unsigned)(d & 63);
}

// ---------------- pass 1b: exclusive scan of bucket totals (incl. self loops) ----------------
__global__ void k_p1b(const int* __restrict__ tails, int N, int NB,
                      int* __restrict__ boff, int* __restrict__ rowoffN) {
    __shared__ int sdata[256];
    __shared__ int carry;
    int t = threadIdx.x;
    if (t == 0) carry = 0;
    __syncthreads();
    for (int c0 = 0; c0 < NB; c0 += 256) {
        int b = c0 + t;
        int tot = 0;
        if (b < NB) {
            for (int x = 0; x < 8; ++x) tot += min(tails[b * 8 + x], CAPB);
            tot += min(64, N - b * 64);          // self loops
        }
        sdata[t] = tot;
        __syncthreads();
        for (int o = 1; o < 256; o <<= 1) {
            int v = (t >= o) ? sdata[t - o] : 0;
            __syncthreads();
            sdata[t] += v;
            __syncthreads();
        }
        if (b < NB) boff[b] = carry + sdata[t] - tot;
        __syncthreads();
        if (t == 255) carry += sdata[255];
        __syncthreads();
    }
    if (t == 0) rowoffN[0] = carry;
}

// ---------------- pass 2: per-bucket local CSR build (LDS hist+scan, window-local writes) ----------------
__global__ __launch_bounds__(256) void k_p2(const unsigned int* __restrict__ bucketBuf,
                                            const int* __restrict__ tails, const int* __restrict__ boff,
                                            int N, int* __restrict__ rowoff, float* __restrict__ dinv,
                                            int* __restrict__ colidx) {
    int b = blockIdx.x;
    int node0 = b * 64;
    int nb = min(64, N - node0);
    __shared__ int psub[9];
    __shared__ int hist[64], curs[64], loff[65];
    __shared__ unsigned int stash[8 * CAPB];
    int t = threadIdx.x;
    if (t == 0) {
        int s = 0;
        for (int x = 0; x < 8; ++x) { psub[x] = s; s += min(tails[b * 8 + x], CAPB); }
        psub[8] = s;
    }
    if (t < 64) hist[t] = 0;
    __syncthreads();
    int T = psub[8];
    for (int i = t; i < T; i += 256) {
        int x = 0;
        while (i >= psub[x + 1]) ++x;
        unsigned int w = bucketBuf[(size_t)(b * 8 + x) * CAPB + (i - psub[x])];
        stash[i] = w;
        atomicAdd(&hist[w & 63], 1);
    }
    __syncthreads();
    if (t == 0) {
        int s = 0;
        for (int j = 0; j < nb; ++j) { loff[j] = s; s += hist[j] + 1; }
        loff[nb] = s;
    }
    __syncthreads();
    int base = boff[b];
    if (t < nb) {
        int node = node0 + t;
        rowoff[node] = base + loff[t];
        dinv[node] = rsqrtf((float)(hist[t] + 1));
        colidx[base + loff[t]] = node;       // self loop first
        curs[t] = loff[t] + 1;
    }
    __syncthreads();
    for (int i = t; i < T; i += 256) {
        unsigned int w = stash[i];
        int slot = atomicAdd(&curs[w & 63], 1);
        colidx[base + slot] = (int)(w >> 6);
    }
}

// ---------------- injected scalar: feat[i][0] = emb[poi[i>>7]][i&127] ----------------
__global__ void k_val(const float* __restrict__ x, const float* __restrict__ emb,
                      int N, float* __restrict__ valv) {
    int i = blockIdx.x * blockDim.x + threadIdx.x;
    if (i < N) {
        int r = i >> 7;
        int poi = (int)x[(size_t)r * FEATN];
        poi = min(max(poi, 0), N - 1);
        valv[i] = emb[(size_t)poi * EMBD + (i & 127)];
    }
}

// ---------------- Wfrag prep: W1[898][64] f32 -> fragment-order bf16, zero-padded ----------------
__global__ void k_prepW(const float* __restrict__ W1, unsigned short* __restrict__ Wf) {
    int id = blockIdx.x * 256 + threadIdx.x;
    if (id >= KT_ALL * 4 * 64 * 8) return;
    int e = id & 7;
    int l = (id >> 3) & 63;
    int nt = (id >> 9) & 3;
    int kt = id >> 11;
    int k = kt * 32 + (l >> 4) * 8 + e;
    int n = nt * 16 + (l & 15);
    float v = (k < FEATN) ? W1[(size_t)k * 64 + n] : 0.f;
    Wf[id] = f2bf(v);
}

// ---------------- GEMM1 via MFMA: no LDS, no barriers ----------------
__global__ __launch_bounds__(256) void k_gemm1m(const float* __restrict__ x,
                                                const unsigned short* __restrict__ Wf,
                                                const float* __restrict__ W1,
                                                const float* __restrict__ valv,
                                                const float* __restrict__ dinv, int N,
                                                float* __restrict__ out) {
    int w = threadIdx.x >> 6;
    int l = threadIdx.x & 63;
    int r0 = blockIdx.x * 64 + w * 16;
    int rowa = r0 + (l & 15);
    if (rowa >= N) rowa = N - 1;
    int kg = l >> 4;
    const float* xrow = x + (size_t)rowa * FEATN + kg * 8;
    const ushort8* wf = (const ushort8*)Wf;

    f32x4 acc[4];
#pragma unroll
    for (int nt = 0; nt < 4; ++nt) acc[nt] = (f32x4){0.f, 0.f, 0.f, 0.f};

    for (int kt = 0; kt < KT_FULL; ++kt) {
        const float* p = xrow + kt * 32;
        float2 q0 = *(const float2*)(p + 0);
        float2 q1 = *(const float2*)(p + 2);
        float2 q2 = *(const float2*)(p + 4);
        float2 q3 = *(const float2*)(p + 6);
        ushort8 u;
        u[0] = f2bf(q0.x); u[1] = f2bf(q0.y);
        u[2] = f2bf(q1.x); u[3] = f2bf(q1.y);
        u[4] = f2bf(q2.x); u[5] = f2bf(q2.y);
        u[6] = f2bf(q3.x); u[7] = f2bf(q3.y);
        if (kt == 0 && kg == 0) u[0] = 0;   // POI-id column zeroed; exact corr in epilogue
        bf16x8 a = as_bf16x8(u);
#pragma unroll
        for (int nt = 0; nt < 4; ++nt) {
            bf16x8 bfr;
            ushort8 ub = wf[(kt * 4 + nt) * 64 + l];
            __builtin_memcpy(&bfr, &ub, 16);
            acc[nt] = __builtin_amdgcn_mfma_f32_16x16x32_bf16(a, bfr, acc[nt], 0, 0, 0);
        }
    }
    {
        ushort8 u = (ushort8)0;
        if (kg == 0) {
            float2 q = *(const float2*)(x + (size_t)rowa * FEATN + 896);
            u[0] = f2bf(q.x);
            u[1] = f2bf(q.y);
        }
        bf16x8 a = as_bf16x8(u);
#pragma unroll
        for (int nt = 0; nt < 4; ++nt) {
            bf16x8 bfr;
            ushort8 ub = wf[(KT_FULL * 4 + nt) * 64 + l];
            __builtin_memcpy(&bfr, &ub, 16);
            acc[nt] = __builtin_amdgcn_mfma_f32_16x16x32_bf16(a, bfr, acc[nt], 0, 0, 0);
        }
    }

    int colb = l & 15;
    int rquad = l >> 4;
    float dv[4], vv[4];
    int rowbase = r0 + rquad * 4;
#pragma unroll
    for (int rg = 0; rg < 4; ++rg) {
        int row = rowbase + rg;
        int rc = (row < N) ? row : (N - 1);
        dv[rg] = dinv[rc];
        vv[rg] = valv[rc];
    }
#pragma unroll
    for (int nt = 0; nt < 4; ++nt) {
        int col = nt * 16 + colb;
        float wcol = W1[col];
#pragma unroll
        for (int rg = 0; rg < 4; ++rg) {
            int row = rowbase + rg;
            if (row < N)
                out[(size_t)row * 64 + col] = dv[rg] * (acc[nt][rg] + vv[rg] * wcol);
        }
    }
}

// ---------------- aggregation, 64 features: wave per node ----------------
template <int EPI>  // 0: leaky ; 1: leaky(t)+t
__global__ __launch_bounds__(256) void k_agg64(const float* __restrict__ hw, const int* __restrict__ rowoff,
                                               const int* __restrict__ colidx, const float* __restrict__ dinv,
                                               const float* __restrict__ bias, int N, float* __restrict__ out) {
    int w = threadIdx.x >> 6;
    int lane = threadIdx.x & 63;
    int v = blockIdx.x * 4 + w;
    if (v >= N) return;
    int beg = rowoff[v], end = rowoff[v + 1];
    float a0 = 0.f, a1 = 0.f, a2 = 0.f, a3 = 0.f;
    int i = beg;
    for (; i + 4 <= end; i += 4) {
        int u0 = colidx[i], u1 = colidx[i + 1], u2 = colidx[i + 2], u3 = colidx[i + 3];
        a0 += hw[(size_t)u0 * 64 + lane];
        a1 += hw[(size_t)u1 * 64 + lane];
        a2 += hw[(size_t)u2 * 64 + lane];
        a3 += hw[(size_t)u3 * 64 + lane];
    }
    for (; i < end; ++i) a0 += hw[(size_t)colidx[i] * 64 + lane];
    float t_ = dinv[v] * ((a0 + a1) + (a2 + a3)) + bias[lane];
    float r = (EPI == 0) ? (t_ >= 0.f ? t_ : 0.01f * t_) : (t_ >= 0.f ? 2.f * t_ : 1.01f * t_);
    out[(size_t)v * 64 + lane] = r;
}

// ---------------- aggregation, 32 features: half-wave per node ----------------
template <int EPI>
__global__ __launch_bounds__(256) void k_agg32(const float* __restrict__ hw, const int* __restrict__ rowoff,
                                               const int* __restrict__ colidx, const float* __restrict__ dinv,
                                               const float* __restrict__ bias, int N, float* __restrict__ out) {
    int sub = threadIdx.x >> 5;
    int lane = threadIdx.x & 31;
    int v = blockIdx.x * 8 + sub;
    if (v >= N) return;
    int beg = rowoff[v], end = rowoff[v + 1];
    float a0 = 0.f, a1 = 0.f, a2 = 0.f, a3 = 0.f;
    int i = beg;
    for (; i + 4 <= end; i += 4) {
        int u0 = colidx[i], u1 = colidx[i + 1], u2 = colidx[i + 2], u3 = colidx[i + 3];
        a0 += hw[(size_t)u0 * 32 + lane];
        a1 += hw[(size_t)u1 * 32 + lane];
        a2 += hw[(size_t)u2 * 32 + lane];
        a3 += hw[(size_t)u3 * 32 + lane];
    }
    for (; i < end; ++i) a0 += hw[(size_t)colidx[i] * 32 + lane];
    float t_ = dinv[v] * ((a0 + a1) + (a2 + a3)) + bias[lane];
    float r = (EPI == 0) ? (t_ >= 0.f ? t_ : 0.01f * t_) : (t_ >= 0.f ? 2.f * t_ : 1.01f * t_);
    out[(size_t)v * 32 + lane] = r;
}

// ---------------- small GEMM ----------------
template <int K, int C>
__global__ __launch_bounds__(256) void k_gemmS(const float* __restrict__ h, const float* __restrict__ W,
                                               const float* __restrict__ dinv, int N, float* __restrict__ out) {
    __shared__ float ws[K * C];
    for (int j = threadIdx.x; j < K * C; j += 256) ws[j] = W[j];
    __syncthreads();
    const int rpb = 256 / C;
    int lr = threadIdx.x / C;
    int col = threadIdx.x % C;
    int row = blockIdx.x * rpb + lr;
    if (row >= N) return;
    const float* hr = h + (size_t)row * K;
    float acc = 0.f;
#pragma unroll
    for (int k = 0; k < K; ++k) acc += hr[k] * ws[k * C + col];
    out[(size_t)row * C + col] = acc * dinv[row];
}

// ---------------- GEMM5 ----------------
__global__ __launch_bounds__(256) void k_gemm5(const float* __restrict__ h, const float* __restrict__ W5,
                                               const float* __restrict__ dinv, int N, float* __restrict__ out) {
    int sub = threadIdx.x >> 5;
    int lane = threadIdx.x & 31;
    int row = blockIdx.x * 8 + sub;
    if (row >= N) return;
    float p = h[(size_t)row * 32 + lane] * W5[lane];
#pragma unroll
    for (int o = 16; o > 0; o >>= 1) p += __shfl_down(p, o, 32);
    if (lane == 0) out[row] = p * dinv[row];
}

// ---------------- aggregation, 1 feature ----------------
__global__ void k_agg1f(const float* __restrict__ hw, const int* __restrict__ rowoff,
                        const int* __restrict__ colidx, const float* __restrict__ dinv,
                        const float* __restrict__ b5, int N, float* __restrict__ vvec) {
    int v = blockIdx.x * blockDim.x + threadIdx.x;
    if (v >= N) return;
    int beg = rowoff[v], end = rowoff[v + 1];
    float s = 0.f;
    for (int i = beg; i < end; ++i) s += hw[colidx[i]];
    float h = dinv[v] * s + b5[0];
    vvec[v] = h >= 0.f ? h : 0.01f * h;
}

// ---------------- fc1 partial ----------------
__global__ __launch_bounds__(128) void k_fc1(const float* __restrict__ vvec, const float* __restrict__ fc1W,
                                             int N, float* __restrict__ accum) {
    int o = threadIdx.x;
    int rpb = (N + gridDim.x - 1) / gridDim.x;
    int r0 = blockIdx.x * rpb;
    int r1 = r0 + rpb;
    if (r1 > N) r1 = N;
    float acc = 0.f;
    for (int r = r0; r < r1; ++r) acc += vvec[r] * fc1W[(size_t)r * 128 + o];
    atomicAdd(&accum[o], acc);
}

// ---------------- fc2 final ----------------
__global__ __launch_bounds__(128) void k_fc2(const float* __restrict__ accum, const float* __restrict__ fc1b,
                                             const float* __restrict__ fc2W, const float* __restrict__ fc2b,
                                             float* __restrict__ outp) {
    __shared__ float s1[128];
    int t = threadIdx.x;
    float h = accum[t] + fc1b[t];
    s1[t] = h > 0.f ? h : 0.f;
    __syncthreads();
    float acc = fc2b[t];
    for (int o = 0; o < 128; ++o) acc += s1[o] * fc2W[o * 128 + t];
    outp[t] = acc > 0.f ? acc : 0.f;
}

extern "C" void kernel_launch(void* const* d_in, const int* in_sizes, int n_in,
                              void* d_out, int out_size, void* d_ws, size_t ws_size,
                              hipStream_t stream) {
    const float* x = (const float*)d_in[0];
    const int* ei = (const int*)d_in[2];
    const float* emb = (const float*)d_in[3];
    const float* W1 = (const float*)d_in[4];
    const float* b1 = (const float*)d_in[5];
    const float* W2 = (const float*)d_in[6];
    const float* b2 = (const float*)d_in[7];
    const float* W3 = (const float*)d_in[8];
    const float* b3 = (const float*)d_in[9];
    const float* W4 = (const float*)d_in[10];
    const float* b4 = (const float*)d_in[11];
    const float* W5 = (const float*)d_in[12];
    const float* b5 = (const float*)d_in[13];
    const float* fc1W = (const float*)d_in[14];
    const float* fc1b = (const float*)d_in[15];
    const float* fc2W = (const float*)d_in[16];
    const float* fc2b = (const float*)d_in[17];

    int N = in_sizes[0] / FEATN;
    int E = in_sizes[2] / 2;
    int NNZ = E + N;
    int NB = (N + 63) / 64;     // buckets of 64 nodes

    char* w = (char*)d_ws;
    auto alloc = [&](size_t bytes) {
        char* p = w;
        w += (bytes + 255) & ~(size_t)255;
        return p;
    };
    float* dinv   = (float*)alloc((size_t)N * 4);
    int*   rowoff = (int*)alloc((size_t)(N + 1) * 4);
    int*   colidx = (int*)alloc((size_t)NNZ * 4);
    float* valv   = (float*)alloc((size_t)N * 4);
    float* accum  = (float*)alloc(512);
    int*   flag   = (int*)alloc(256);
    int*   tails  = (int*)alloc((size_t)NB * 8 * 4);
    int*   boff   = (int*)alloc((size_t)NB * 4);
    unsigned int* bucketBuf = (unsigned int*)alloc((size_t)NB * 8 * CAPB * 4);
    unsigned short* Wf = (unsigned short*)alloc((size_t)KT_ALL * 4 * 64 * 8 * 2);
    float* bufA   = (float*)alloc((size_t)N * 64 * 4);
    float* bufB   = (float*)alloc((size_t)N * 64 * 4);
    float* vvec   = (float*)alloc((size_t)N * 4);

    int nb = (N + 255) / 256;

    k_detect<<<1, 256, 0, stream>>>(ei, flag);
    k_init<<<nb, 256, 0, stream>>>(tails, NB * 8, accum, N);
    k_p1<<<(E + 255) / 256, 256, 0, stream>>>(ei, E, N, flag, tails, bucketBuf);
    k_p1b<<<1, 256, 0, stream>>>(tails, N, NB, boff, rowoff + N);
    k_p2<<<NB, 256, 0, stream>>>(bucketBuf, tails, boff, N, rowoff, dinv, colidx);
    k_val<<<nb, 256, 0, stream>>>(x, emb, N, valv);
    k_prepW<<<(KT_ALL * 4 * 64 * 8 + 255) / 256, 256, 0, stream>>>(W1, Wf);

    k_gemm1m<<<(N + 63) / 64, 256, 0, stream>>>(x, Wf, W1, valv, dinv, N, bufA);
    k_agg64<0><<<(N + 3) / 4, 256, 0, stream>>>(bufA, rowoff, colidx, dinv, b1, N, bufB);

    k_gemmS<64, 32><<<(N + 7) / 8, 256, 0, stream>>>(bufB, W2, dinv, N, bufA);
    k_agg32<0><<<(N + 7) / 8, 256, 0, stream>>>(bufA, rowoff, colidx, dinv, b2, N, bufB);

    k_gemmS<32, 32><<<(N + 7) / 8, 256, 0, stream>>>(bufB, W3, dinv, N, bufA);
    k_agg32<1><<<(N + 7) / 8, 256, 0, stream>>>(bufA, rowoff, colidx, dinv, b3, N, bufB);

    k_gemmS<32, 32><<<(N + 7) / 8, 256, 0, stream>>>(bufB, W4, dinv, N, bufA);
    k_agg32<1><<<(N + 7) / 8, 256, 0, stream>>>(bufA, rowoff, colidx, dinv, b4, N, bufB);

    k_gemm5<<<(N + 7) / 8, 256, 0, stream>>>(bufB, W5, dinv, N, bufA);
    k_agg1f<<<nb, 256, 0, stream>>>(bufA, rowoff, colidx, dinv, b5, N, vvec);

    k_fc1<<<300, 128, 0, stream>>>(vvec, fc1W, N, accum);
    k_fc2<<<1, 128, 0, stream>>>(accum, fc1b, fc2W, fc2b, (float*)d_out);
}

// Round 5
// 326.034 us; speedup vs baseline: 1.5596x; 1.1587x over previous
//
#include <hip/hip_runtime.h>
#include <hip/hip_bf16.h>

#define FEATN 898
#define EMBD 128
#define KT_FULL 28          // 28 full k-tiles of 32 (896), tail handles k=896..897
#define KT_ALL 29           // padded tiles in Wfrag
#define CBITS 8
#define CSZ 256             // nodes per coarse bucket
#define CAP2 12288          // per-bucket capacity (mean ~8183, +45 sigma)
#define EPB 8192            // edges per p1 block

typedef __bf16 bf16x8 __attribute__((ext_vector_type(8)));
typedef float f32x4 __attribute__((ext_vector_type(4)));
typedef unsigned short ushort8 __attribute__((ext_vector_type(8)));

__device__ inline unsigned short f2bf(float f) {
    unsigned int u = __float_as_uint(f);
    unsigned int r = u + 0x7fffu + ((u >> 16) & 1u);   // RNE
    return (unsigned short)(r >> 16);
}
__device__ inline bf16x8 as_bf16x8(ushort8 u) {
    bf16x8 r;
    __builtin_memcpy(&r, &u, 16);
    return r;
}

// ---------------- layout probe: int32 vs int64(lo,hi) storage of edge_index ----------------
__global__ void k_detect(const int* __restrict__ ei32, int* __restrict__ flag) {
    __shared__ int any;
    int t = threadIdx.x;
    if (t == 0) any = 0;
    __syncthreads();
    if (ei32[2 * t + 1] != 0) atomicOr(&any, 1);
    __syncthreads();
    if (t == 0) flag[0] = any;   // 1 = int32 layout, 0 = int64 layout
}

// ---------------- init: zero bucket tails + fc1 accumulator ----------------
__global__ void k_init(int* __restrict__ gtails, int nbc, float* __restrict__ accum) {
    int i = blockIdx.x * blockDim.x + threadIdx.x;
    if (i < nbc) gtails[i] = 0;
    if (i < 128) accum[i] = 0.f;
}

// ---------------- p1: counting-sort pass — per-block hist, reserve runs, write payloads ----------------
__global__ __launch_bounds__(256) void k_p1(const int* __restrict__ ei, int E, int N, int nbc,
                                            const int* __restrict__ flag,
                                            int* __restrict__ gtails, unsigned int* __restrict__ bb) {
    __shared__ int hist[256], curs[256];
    int t = threadIdx.x;
    hist[t] = 0;
    __syncthreads();
    int e0 = blockIdx.x * EPB;
    int f = flag[0];
#pragma unroll
    for (int i = 0; i < EPB / 256; ++i) {
        int e = e0 + i * 256 + t;
        if (e < E) {
            int d = f ? ei[(size_t)E + e] : ei[2 * ((size_t)E + e)];
            d = min(max(d, 0), N - 1);
            atomicAdd(&hist[d >> CBITS], 1);
        }
    }
    __syncthreads();
    if (t < nbc) curs[t] = (hist[t] > 0) ? atomicAdd(&gtails[t], hist[t]) : 0;
    __syncthreads();
#pragma unroll
    for (int i = 0; i < EPB / 256; ++i) {
        int e = e0 + i * 256 + t;
        if (e < E) {
            int s = f ? ei[e] : ei[2 * (size_t)e];
            int d = f ? ei[(size_t)E + e] : ei[2 * ((size_t)E + e)];
            s = min(max(s, 0), N - 1);
            d = min(max(d, 0), N - 1);
            int c = d >> CBITS;
            int pos = atomicAdd(&curs[c], 1);
            if (pos < CAP2) bb[(size_t)c * CAP2 + pos] = ((unsigned)s << CBITS) | (unsigned)(d & (CSZ - 1));
        }
    }
}

// ---------------- p1b: exclusive scan of bucket totals (incl. self loops) ----------------
__global__ void k_p1b(const int* __restrict__ gtails, int N, int nbc,
                      int* __restrict__ boff, int* __restrict__ rowoffN) {
    __shared__ int s[256];
    int t = threadIdx.x;
    int tot = 0;
    if (t < nbc) tot = min(gtails[t], CAP2) + min(CSZ, N - t * CSZ);
    s[t] = tot;
    __syncthreads();
    for (int o = 1; o < 256; o <<= 1) {
        int v = (t >= o) ? s[t - o] : 0;
        __syncthreads();
        s[t] += v;
        __syncthreads();
    }
    if (t < nbc) boff[t] = s[t] - tot;
    if (t == 255) rowoffN[0] = s[255];
}

// ---------------- p2: per-bucket CSR build in LDS, window-local writes ----------------
__global__ __launch_bounds__(256) void k_p2(const unsigned int* __restrict__ bb,
                                            const int* __restrict__ gtails, const int* __restrict__ boff,
                                            int N, int* __restrict__ rowoff, float* __restrict__ dinv,
                                            int* __restrict__ colidx) {
    __shared__ unsigned int stash[CAP2];     // 48 KB
    __shared__ int hist[CSZ], curs[CSZ], sc[CSZ];
    int b = blockIdx.x;
    int t = threadIdx.x;
    int node0 = b * CSZ;
    int nbn = min(CSZ, N - node0);
    int T = min(gtails[b], CAP2);
    hist[t] = 0;
    __syncthreads();
    for (int i = t; i < T; i += 256) {
        unsigned int u = bb[(size_t)b * CAP2 + i];
        stash[i] = u;
        atomicAdd(&hist[u & (CSZ - 1)], 1);
    }
    __syncthreads();
    // inclusive scan of (hist+1 self loop) over nbn nodes
    int v = (t < nbn) ? hist[t] + 1 : 0;
    sc[t] = v;
    __syncthreads();
    for (int o = 1; o < 256; o <<= 1) {
        int x_ = (t >= o) ? sc[t - o] : 0;
        __syncthreads();
        sc[t] += x_;
        __syncthreads();
    }
    int base = boff[b];
    if (t < nbn) {
        int node = node0 + t;
        int ex = sc[t] - v;
        rowoff[node] = base + ex;
        dinv[node] = rsqrtf((float)(hist[t] + 1));
        colidx[base + ex] = node;            // self loop first
        curs[t] = ex + 1;
    }
    __syncthreads();
    for (int i = t; i < T; i += 256) {
        unsigned int u = stash[i];
        int slot = atomicAdd(&curs[u & (CSZ - 1)], 1);
        colidx[base + slot] = (int)(u >> CBITS);
    }
}

// ---------------- injected scalar: feat[i][0] = emb[poi[i>>7]][i&127] ----------------
__global__ void k_val(const float* __restrict__ x, const float* __restrict__ emb,
                      int N, float* __restrict__ valv) {
    int i = blockIdx.x * blockDim.x + threadIdx.x;
    if (i < N) {
        int r = i >> 7;
        int poi = (int)x[(size_t)r * FEATN];
        poi = min(max(poi, 0), N - 1);
        valv[i] = emb[(size_t)poi * EMBD + (i & 127)];
    }
}

// ---------------- Wfrag prep: W1[898][64] f32 -> fragment-order bf16, zero-padded ----------------
__global__ void k_prepW(const float* __restrict__ W1, unsigned short* __restrict__ Wf) {
    int id = blockIdx.x * 256 + threadIdx.x;
    if (id >= KT_ALL * 4 * 64 * 8) return;
    int e = id & 7;
    int l = (id >> 3) & 63;
    int nt = (id >> 9) & 3;
    int kt = id >> 11;
    int k = kt * 32 + (l >> 4) * 8 + e;
    int n = nt * 16 + (l & 15);
    float v = (k < FEATN) ? W1[(size_t)k * 64 + n] : 0.f;
    Wf[id] = f2bf(v);
}

// ---------------- GEMM1 via MFMA, K-split x2 over 8 waves; LDS combine ----------------
__global__ __launch_bounds__(512) void k_gemm1m(const float* __restrict__ x,
                                                const unsigned short* __restrict__ Wf,
                                                const float* __restrict__ W1,
                                                const float* __restrict__ valv,
                                                const float* __restrict__ dinv, int N,
                                                float* __restrict__ out) {
    __shared__ float red[4][16][66];        // stride 66: 4*66 % 32 == 8 -> 2-way (free)
    int w = threadIdx.x >> 6;
    int l = threadIdx.x & 63;
    int half = w >> 2;                      // 0: k<448, 1: k>=448
    int wsub = w & 3;
    int r0 = blockIdx.x * 64 + wsub * 16;
    int rowa = r0 + (l & 15);
    if (rowa >= N) rowa = N - 1;
    int kg = l >> 4;
    const float* xrow = x + (size_t)rowa * FEATN + kg * 8;
    const ushort8* wf = (const ushort8*)Wf;

    f32x4 acc[4];
#pragma unroll
    for (int nt = 0; nt < 4; ++nt) acc[nt] = (f32x4){0.f, 0.f, 0.f, 0.f};

    int ktBeg = half ? 14 : 0;
    int ktEnd = half ? KT_FULL : 14;
    const float* p0 = xrow + ktBeg * 32;
    float2 q0 = *(const float2*)(p0 + 0);
    float2 q1 = *(const float2*)(p0 + 2);
    float2 q2 = *(const float2*)(p0 + 4);
    float2 q3 = *(const float2*)(p0 + 6);

    for (int kt = ktBeg; kt < ktEnd; ++kt) {
        ushort8 u;
        u[0] = f2bf(q0.x); u[1] = f2bf(q0.y);
        u[2] = f2bf(q1.x); u[3] = f2bf(q1.y);
        u[4] = f2bf(q2.x); u[5] = f2bf(q2.y);
        u[6] = f2bf(q3.x); u[7] = f2bf(q3.y);
        if (kt + 1 < ktEnd) {               // prefetch next k-tile
            const float* pn = xrow + (kt + 1) * 32;
            q0 = *(const float2*)(pn + 0);
            q1 = *(const float2*)(pn + 2);
            q2 = *(const float2*)(pn + 4);
            q3 = *(const float2*)(pn + 6);
        }
        if (kt == 0 && kg == 0) u[0] = 0;   // POI-id column zeroed; exact corr in epilogue
        bf16x8 a = as_bf16x8(u);
#pragma unroll
        for (int nt = 0; nt < 4; ++nt) {
            bf16x8 bfr;
            ushort8 ub = wf[(kt * 4 + nt) * 64 + l];
            __builtin_memcpy(&bfr, &ub, 16);
            acc[nt] = __builtin_amdgcn_mfma_f32_16x16x32_bf16(a, bfr, acc[nt], 0, 0, 0);
        }
    }
    if (half) {                              // tail k = 896..897
        ushort8 u = (ushort8)0;
        if (kg == 0) {
            float2 q = *(const float2*)(x + (size_t)rowa * FEATN + 896);
            u[0] = f2bf(q.x);
            u[1] = f2bf(q.y);
        }
        bf16x8 a = as_bf16x8(u);
#pragma unroll
        for (int nt = 0; nt < 4; ++nt) {
            bf16x8 bfr;
            ushort8 ub = wf[(KT_FULL * 4 + nt) * 64 + l];
            __builtin_memcpy(&bfr, &ub, 16);
            acc[nt] = __builtin_amdgcn_mfma_f32_16x16x32_bf16(a, bfr, acc[nt], 0, 0, 0);
        }
    }

    int colb = l & 15;
    int rquad = l >> 4;
    if (!half) {
#pragma unroll
        for (int nt = 0; nt < 4; ++nt)
#pragma unroll
            for (int rg = 0; rg < 4; ++rg)
                red[wsub][rquad * 4 + rg][nt * 16 + colb] = acc[nt][rg];
    }
    __syncthreads();
    if (half) {
        float dv[4], vv[4];
        int rowbase = r0 + rquad * 4;
#pragma unroll
        for (int rg = 0; rg < 4; ++rg) {
            int row = rowbase + rg;
            int rc = (row < N) ? row : (N - 1);
            dv[rg] = dinv[rc];
            vv[rg] = valv[rc];
        }
#pragma unroll
        for (int nt = 0; nt < 4; ++nt) {
            int col = nt * 16 + colb;
            float wcol = W1[col];
#pragma unroll
            for (int rg = 0; rg < 4; ++rg) {
                int row = rowbase + rg;
                if (row < N)
                    out[(size_t)row * 64 + col] =
                        dv[rg] * (acc[nt][rg] + red[wsub][rquad * 4 + rg][col] + vv[rg] * wcol);
            }
        }
    }
}

// ---------------- aggregation, 64 features: wave per node ----------------
template <int EPI>  // 0: leaky ; 1: leaky(t)+t
__global__ __launch_bounds__(256) void k_agg64(const float* __restrict__ hw, const int* __restrict__ rowoff,
                                               const int* __restrict__ colidx, const float* __restrict__ dinv,
                                               const float* __restrict__ bias, int N, float* __restrict__ out) {
    int w = threadIdx.x >> 6;
    int lane = threadIdx.x & 63;
    int v = blockIdx.x * 4 + w;
    if (v >= N) return;
    int beg = rowoff[v], end = rowoff[v + 1];
    float a0 = 0.f, a1 = 0.f, a2 = 0.f, a3 = 0.f;
    int i = beg;
    for (; i + 4 <= end; i += 4) {
        int u0 = colidx[i], u1 = colidx[i + 1], u2 = colidx[i + 2], u3 = colidx[i + 3];
        a0 += hw[(size_t)u0 * 64 + lane];
        a1 += hw[(size_t)u1 * 64 + lane];
        a2 += hw[(size_t)u2 * 64 + lane];
        a3 += hw[(size_t)u3 * 64 + lane];
    }
    for (; i < end; ++i) a0 += hw[(size_t)colidx[i] * 64 + lane];
    float t_ = dinv[v] * ((a0 + a1) + (a2 + a3)) + bias[lane];
    float r = (EPI == 0) ? (t_ >= 0.f ? t_ : 0.01f * t_) : (t_ >= 0.f ? 2.f * t_ : 1.01f * t_);
    out[(size_t)v * 64 + lane] = r;
}

// ---------------- aggregation, 32 features: half-wave per node ----------------
template <int EPI>
__global__ __launch_bounds__(256) void k_agg32(const float* __restrict__ hw, const int* __restrict__ rowoff,
                                               const int* __restrict__ colidx, const float* __restrict__ dinv,
                                               const float* __restrict__ bias, int N, float* __restrict__ out) {
    int sub = threadIdx.x >> 5;
    int lane = threadIdx.x & 31;
    int v = blockIdx.x * 8 + sub;
    if (v >= N) return;
    int beg = rowoff[v], end = rowoff[v + 1];
    float a0 = 0.f, a1 = 0.f, a2 = 0.f, a3 = 0.f;
    int i = beg;
    for (; i + 4 <= end; i += 4) {
        int u0 = colidx[i], u1 = colidx[i + 1], u2 = colidx[i + 2], u3 = colidx[i + 3];
        a0 += hw[(size_t)u0 * 32 + lane];
        a1 += hw[(size_t)u1 * 32 + lane];
        a2 += hw[(size_t)u2 * 32 + lane];
        a3 += hw[(size_t)u3 * 32 + lane];
    }
    for (; i < end; ++i) a0 += hw[(size_t)colidx[i] * 32 + lane];
    float t_ = dinv[v] * ((a0 + a1) + (a2 + a3)) + bias[lane];
    float r = (EPI == 0) ? (t_ >= 0.f ? t_ : 0.01f * t_) : (t_ >= 0.f ? 2.f * t_ : 1.01f * t_);
    out[(size_t)v * 32 + lane] = r;
}

// ---------------- small GEMM ----------------
template <int K, int C>
__global__ __launch_bounds__(256) void k_gemmS(const float* __restrict__ h, const float* __restrict__ W,
                                               const float* __restrict__ dinv, int N, float* __restrict__ out) {
    __shared__ float ws[K * C];
    for (int j = threadIdx.x; j < K * C; j += 256) ws[j] = W[j];
    __syncthreads();
    const int rpb = 256 / C;
    int lr = threadIdx.x / C;
    int col = threadIdx.x % C;
    int row = blockIdx.x * rpb + lr;
    if (row >= N) return;
    const float* hr = h + (size_t)row * K;
    float acc = 0.f;
#pragma unroll
    for (int k = 0; k < K; ++k) acc += hr[k] * ws[k * C + col];
    out[(size_t)row * C + col] = acc * dinv[row];
}

// ---------------- GEMM5 ----------------
__global__ __launch_bounds__(256) void k_gemm5(const float* __restrict__ h, const float* __restrict__ W5,
                                               const float* __restrict__ dinv, int N, float* __restrict__ out) {
    int sub = threadIdx.x >> 5;
    int lane = threadIdx.x & 31;
    int row = blockIdx.x * 8 + sub;
    if (row >= N) return;
    float p = h[(size_t)row * 32 + lane] * W5[lane];
#pragma unroll
    for (int o = 16; o > 0; o >>= 1) p += __shfl_down(p, o, 32);
    if (lane == 0) out[row] = p * dinv[row];
}

// ---------------- aggregation, 1 feature ----------------
__global__ void k_agg1f(const float* __restrict__ hw, const int* __restrict__ rowoff,
                        const int* __restrict__ colidx, const float* __restrict__ dinv,
                        const float* __restrict__ b5, int N, float* __restrict__ vvec) {
    int v = blockIdx.x * blockDim.x + threadIdx.x;
    if (v >= N) return;
    int beg = rowoff[v], end = rowoff[v + 1];
    float s = 0.f;
    for (int i = beg; i < end; ++i) s += hw[colidx[i]];
    float h = dinv[v] * s + b5[0];
    vvec[v] = h >= 0.f ? h : 0.01f * h;
}

// ---------------- fc1 partial ----------------
__global__ __launch_bounds__(128) void k_fc1(const float* __restrict__ vvec, const float* __restrict__ fc1W,
                                             int N, float* __restrict__ accum) {
    int o = threadIdx.x;
    int rpb = (N + gridDim.x - 1) / gridDim.x;
    int r0 = blockIdx.x * rpb;
    int r1 = r0 + rpb;
    if (r1 > N) r1 = N;
    float acc = 0.f;
    for (int r = r0; r < r1; ++r) acc += vvec[r] * fc1W[(size_t)r * 128 + o];
    atomicAdd(&accum[o], acc);
}

// ---------------- fc2 final ----------------
__global__ __launch_bounds__(128) void k_fc2(const float* __restrict__ accum, const float* __restrict__ fc1b,
                                             const float* __restrict__ fc2W, const float* __restrict__ fc2b,
                                             float* __restrict__ outp) {
    __shared__ float s1[128];
    int t = threadIdx.x;
    float h = accum[t] + fc1b[t];
    s1[t] = h > 0.f ? h : 0.f;
    __syncthreads();
    float acc = fc2b[t];
    for (int o = 0; o < 128; ++o) acc += s1[o] * fc2W[o * 128 + t];
    outp[t] = acc > 0.f ? acc : 0.f;
}

extern "C" void kernel_launch(void* const* d_in, const int* in_sizes, int n_in,
                              void* d_out, int out_size, void* d_ws, size_t ws_size,
                              hipStream_t stream) {
    const float* x = (const float*)d_in[0];
    const int* ei = (const int*)d_in[2];
    const float* emb = (const float*)d_in[3];
    const float* W1 = (const float*)d_in[4];
    const float* b1 = (const float*)d_in[5];
    const float* W2 = (const float*)d_in[6];
    const float* b2 = (const float*)d_in[7];
    const float* W3 = (const float*)d_in[8];
    const float* b3 = (const float*)d_in[9];
    const float* W4 = (const float*)d_in[10];
    const float* b4 = (const float*)d_in[11];
    const float* W5 = (const float*)d_in[12];
    const float* b5 = (const float*)d_in[13];
    const float* fc1W = (const float*)d_in[14];
    const float* fc1b = (const float*)d_in[15];
    const float* fc2W = (const float*)d_in[16];
    const float* fc2b = (const float*)d_in[17];

    int N = in_sizes[0] / FEATN;
    int E = in_sizes[2] / 2;
    int NNZ = E + N;
    int NBC = (N + CSZ - 1) / CSZ;      // coarse buckets of 256 nodes

    char* w = (char*)d_ws;
    auto alloc = [&](size_t bytes) {
        char* p = w;
        w += (bytes + 255) & ~(size_t)255;
        return p;
    };
    float* dinv   = (float*)alloc((size_t)N * 4);
    int*   rowoff = (int*)alloc((size_t)(N + 1) * 4);
    int*   colidx = (int*)alloc((size_t)NNZ * 4);
    float* valv   = (float*)alloc((size_t)N * 4);
    float* accum  = (float*)alloc(512);
    int*   flag   = (int*)alloc(256);
    int*   gtails = (int*)alloc((size_t)NBC * 4);
    int*   boff   = (int*)alloc((size_t)NBC * 4);
    unsigned int* bb = (unsigned int*)alloc((size_t)NBC * CAP2 * 4);
    unsigned short* Wf = (unsigned short*)alloc((size_t)KT_ALL * 4 * 64 * 8 * 2);
    float* bufA   = (float*)alloc((size_t)N * 64 * 4);
    float* bufB   = (float*)alloc((size_t)N * 64 * 4);
    float* vvec   = (float*)alloc((size_t)N * 4);

    int nb = (N + 255) / 256;

    k_detect<<<1, 256, 0, stream>>>(ei, flag);
    k_init<<<1, 256, 0, stream>>>(gtails, NBC, accum);
    k_p1<<<(E + EPB - 1) / EPB, 256, 0, stream>>>(ei, E, N, NBC, flag, gtails, bb);
    k_p1b<<<1, 256, 0, stream>>>(gtails, N, NBC, boff, rowoff + N);
    k_p2<<<NBC, 256, 0, stream>>>(bb, gtails, boff, N, rowoff, dinv, colidx);
    k_val<<<nb, 256, 0, stream>>>(x, emb, N, valv);
    k_prepW<<<(KT_ALL * 4 * 64 * 8 + 255) / 256, 256, 0, stream>>>(W1, Wf);

    k_gemm1m<<<(N + 63) / 64, 512, 0, stream>>>(x, Wf, W1, valv, dinv, N, bufA);
    k_agg64<0><<<(N + 3) / 4, 256, 0, stream>>>(bufA, rowoff, colidx, dinv, b1, N, bufB);

    k_gemmS<64, 32><<<(N + 7) / 8, 256, 0, stream>>>(bufB, W2, dinv, N, bufA);
    k_agg32<0><<<(N + 7) / 8, 256, 0, stream>>>(bufA, rowoff, colidx, dinv, b2, N, bufB);

    k_gemmS<32, 32><<<(N + 7) / 8, 256, 0, stream>>>(bufB, W3, dinv, N, bufA);
    k_agg32<1><<<(N + 7) / 8, 256, 0, stream>>>(bufA, rowoff, colidx, dinv, b3, N, bufB);

    k_gemmS<32, 32><<<(N + 7) / 8, 256, 0, stream>>>(bufB, W4, dinv, N, bufA);
    k_agg32<1><<<(N + 7) / 8, 256, 0, stream>>>(bufA, rowoff, colidx, dinv, b4, N, bufB);

    k_gemm5<<<(N + 7) / 8, 256, 0, stream>>>(bufB, W5, dinv, N, bufA);
    k_agg1f<<<nb, 256, 0, stream>>>(bufA, rowoff, colidx, dinv, b5, N, vvec);

    k_fc1<<<300, 128, 0, stream>>>(vvec, fc1W, N, accum);
    k_fc2<<<1, 128, 0, stream>>>(accum, fc1b, fc2W, fc2b, (float*)d_out);
}

// Round 6
// 323.441 us; speedup vs baseline: 1.5721x; 1.0080x over previous
//
#include <hip/hip_runtime.h>
#include <hip/hip_bf16.h>

#define FEATN 898
#define EMBD 128
#define KT_FULL 28          // 28 full k-tiles of 32 (896), tile 28 handles k=896..897
#define KT_ALL 29           // padded tiles in Wfrag
#define CHUNK 8             // k-tiles staged per LDS chunk (32 KB)
#define CBITS 8
#define CSZ 256             // nodes per coarse bucket
#define CAP2 12288          // per-bucket capacity (mean ~8183, +45 sigma)
#define EPB 8192            // edges per p1 block

typedef __bf16 bf16x8 __attribute__((ext_vector_type(8)));
typedef float f32x4 __attribute__((ext_vector_type(4)));
typedef unsigned short ushort8 __attribute__((ext_vector_type(8)));

__device__ inline unsigned short f2bf(float f) {
    unsigned int u = __float_as_uint(f);
    unsigned int r = u + 0x7fffu + ((u >> 16) & 1u);   // RNE
    return (unsigned short)(r >> 16);
}
__device__ inline bf16x8 as_bf16x8(ushort8 u) {
    bf16x8 r;
    __builtin_memcpy(&r, &u, 16);
    return r;
}

// ---------------- layout probe: int32 vs int64(lo,hi) storage of edge_index ----------------
__global__ void k_detect(const int* __restrict__ ei32, int* __restrict__ flag) {
    __shared__ int any;
    int t = threadIdx.x;
    if (t == 0) any = 0;
    __syncthreads();
    if (ei32[2 * t + 1] != 0) atomicOr(&any, 1);
    __syncthreads();
    if (t == 0) flag[0] = any;   // 1 = int32 layout, 0 = int64 layout
}

// ---------------- init: zero bucket tails + fc1 accumulator ----------------
__global__ void k_init(int* __restrict__ gtails, int nbc, float* __restrict__ accum) {
    int i = blockIdx.x * blockDim.x + threadIdx.x;
    if (i < nbc) gtails[i] = 0;
    if (i < 128) accum[i] = 0.f;
}

// ---------------- p1: counting-sort pass — per-block hist, reserve runs, write payloads ----------------
__global__ __launch_bounds__(256) void k_p1(const int* __restrict__ ei, int E, int N, int nbc,
                                            const int* __restrict__ flag,
                                            int* __restrict__ gtails, unsigned int* __restrict__ bb) {
    __shared__ int hist[256], curs[256];
    int t = threadIdx.x;
    hist[t] = 0;
    __syncthreads();
    int e0 = blockIdx.x * EPB;
    int f = flag[0];
#pragma unroll
    for (int i = 0; i < EPB / 256; ++i) {
        int e = e0 + i * 256 + t;
        if (e < E) {
            int d = f ? ei[(size_t)E + e] : ei[2 * ((size_t)E + e)];
            d = min(max(d, 0), N - 1);
            atomicAdd(&hist[d >> CBITS], 1);
        }
    }
    __syncthreads();
    if (t < nbc) curs[t] = (hist[t] > 0) ? atomicAdd(&gtails[t], hist[t]) : 0;
    __syncthreads();
#pragma unroll
    for (int i = 0; i < EPB / 256; ++i) {
        int e = e0 + i * 256 + t;
        if (e < E) {
            int s = f ? ei[e] : ei[2 * (size_t)e];
            int d = f ? ei[(size_t)E + e] : ei[2 * ((size_t)E + e)];
            s = min(max(s, 0), N - 1);
            d = min(max(d, 0), N - 1);
            int c = d >> CBITS;
            int pos = atomicAdd(&curs[c], 1);
            if (pos < CAP2) bb[(size_t)c * CAP2 + pos] = ((unsigned)s << CBITS) | (unsigned)(d & (CSZ - 1));
        }
    }
}

// ---------------- p1b: exclusive scan of bucket totals (incl. self loops) ----------------
__global__ void k_p1b(const int* __restrict__ gtails, int N, int nbc,
                      int* __restrict__ boff, int* __restrict__ rowoffN) {
    __shared__ int s[256];
    int t = threadIdx.x;
    int tot = 0;
    if (t < nbc) tot = min(gtails[t], CAP2) + min(CSZ, N - t * CSZ);
    s[t] = tot;
    __syncthreads();
    for (int o = 1; o < 256; o <<= 1) {
        int v = (t >= o) ? s[t - o] : 0;
        __syncthreads();
        s[t] += v;
        __syncthreads();
    }
    if (t < nbc) boff[t] = s[t] - tot;
    if (t == 255) rowoffN[0] = s[255];
}

// ---------------- p2: per-bucket CSR build in LDS, window-local writes ----------------
__global__ __launch_bounds__(256) void k_p2(const unsigned int* __restrict__ bb,
                                            const int* __restrict__ gtails, const int* __restrict__ boff,
                                            int N, int* __restrict__ rowoff, float* __restrict__ dinv,
                                            int* __restrict__ colidx) {
    __shared__ unsigned int stash[CAP2];     // 48 KB
    __shared__ int hist[CSZ], curs[CSZ], sc[CSZ];
    int b = blockIdx.x;
    int t = threadIdx.x;
    int node0 = b * CSZ;
    int nbn = min(CSZ, N - node0);
    int T = min(gtails[b], CAP2);
    hist[t] = 0;
    __syncthreads();
    for (int i = t; i < T; i += 256) {
        unsigned int u = bb[(size_t)b * CAP2 + i];
        stash[i] = u;
        atomicAdd(&hist[u & (CSZ - 1)], 1);
    }
    __syncthreads();
    int v = (t < nbn) ? hist[t] + 1 : 0;
    sc[t] = v;
    __syncthreads();
    for (int o = 1; o < 256; o <<= 1) {
        int x_ = (t >= o) ? sc[t - o] : 0;
        __syncthreads();
        sc[t] += x_;
        __syncthreads();
    }
    int base = boff[b];
    if (t < nbn) {
        int node = node0 + t;
        int ex = sc[t] - v;
        rowoff[node] = base + ex;
        dinv[node] = rsqrtf((float)(hist[t] + 1));
        colidx[base + ex] = node;            // self loop first
        curs[t] = ex + 1;
    }
    __syncthreads();
    for (int i = t; i < T; i += 256) {
        unsigned int u = stash[i];
        int slot = atomicAdd(&curs[u & (CSZ - 1)], 1);
        colidx[base + slot] = (int)(u >> CBITS);
    }
}

// ---------------- injected scalar: feat[i][0] = emb[poi[i>>7]][i&127] ----------------
__global__ void k_val(const float* __restrict__ x, const float* __restrict__ emb,
                      int N, float* __restrict__ valv) {
    int i = blockIdx.x * blockDim.x + threadIdx.x;
    if (i < N) {
        int r = i >> 7;
        int poi = (int)x[(size_t)r * FEATN];
        poi = min(max(poi, 0), N - 1);
        valv[i] = emb[(size_t)poi * EMBD + (i & 127)];
    }
}

// ---------------- Wfrag prep: W1[898][64] f32 -> fragment-order bf16, zero-padded ----------------
__global__ void k_prepW(const float* __restrict__ W1, unsigned short* __restrict__ Wf) {
    int id = blockIdx.x * 256 + threadIdx.x;
    if (id >= KT_ALL * 4 * 64 * 8) return;
    int e = id & 7;
    int l = (id >> 3) & 63;
    int nt = (id >> 9) & 3;
    int kt = id >> 11;
    int k = kt * 32 + (l >> 4) * 8 + e;
    int n = nt * 16 + (l & 15);
    float v = (k < FEATN) ? W1[(size_t)k * 64 + n] : 0.f;
    Wf[id] = f2bf(v);
}

// ---------------- GEMM1 via MFMA: Wf staged through LDS in chunks; x reg-prefetched ----------------
__global__ __launch_bounds__(256, 4) void k_gemm1m(const float* __restrict__ x,
                                                   const unsigned short* __restrict__ Wf,
                                                   const float* __restrict__ W1,
                                                   const float* __restrict__ valv,
                                                   const float* __restrict__ dinv, int N,
                                                   float* __restrict__ out) {
    __shared__ ushort8 wlds[CHUNK * 4 * 64];   // 32 KB
    int w = threadIdx.x >> 6;
    int l = threadIdx.x & 63;
    int r0 = blockIdx.x * 64 + w * 16;
    int rowa = r0 + (l & 15);
    if (rowa >= N) rowa = N - 1;               // clamp for A-loads; stores guarded below
    int kg = l >> 4;
    const float* xrow = x + (size_t)rowa * FEATN + kg * 8;
    const ushort8* wfg = (const ushort8*)Wf;

    f32x4 acc[4];
#pragma unroll
    for (int nt = 0; nt < 4; ++nt) acc[nt] = (f32x4){0.f, 0.f, 0.f, 0.f};

    // prefetch first x k-tile
    float2 q0 = *(const float2*)(xrow + 0);
    float2 q1 = *(const float2*)(xrow + 2);
    float2 q2 = *(const float2*)(xrow + 4);
    float2 q3 = *(const float2*)(xrow + 6);

    for (int c0 = 0; c0 < KT_ALL; c0 += CHUNK) {
        int nkt = min(CHUNK, KT_ALL - c0);
        __syncthreads();                       // previous chunk's reads complete
        for (int i = threadIdx.x; i < nkt * 256; i += 256)
            wlds[i] = wfg[(size_t)c0 * 256 + i];
        __syncthreads();
        for (int kc = 0; kc < nkt; ++kc) {
            int kt = c0 + kc;
            // convert current x tile to bf16
            ushort8 u;
            u[0] = f2bf(q0.x); u[1] = f2bf(q0.y);
            u[2] = f2bf(q1.x); u[3] = f2bf(q1.y);
            u[4] = f2bf(q2.x); u[5] = f2bf(q2.y);
            u[6] = f2bf(q3.x); u[7] = f2bf(q3.y);
            // prefetch next x tile
            int ktn = kt + 1;
            if (ktn < KT_FULL) {
                const float* pn = xrow + ktn * 32;
                q0 = *(const float2*)(pn + 0);
                q1 = *(const float2*)(pn + 2);
                q2 = *(const float2*)(pn + 4);
                q3 = *(const float2*)(pn + 6);
            } else if (ktn == KT_FULL) {       // tail tile: k=896..897, only kg==0 lanes
                float2 z = make_float2(0.f, 0.f);
                q0 = (kg == 0) ? *(const float2*)(x + (size_t)rowa * FEATN + 896) : z;
                q1 = z; q2 = z; q3 = z;
            }
            if (kt == 0 && kg == 0) u[0] = 0;  // POI-id column zeroed; exact corr in epilogue
            bf16x8 a = as_bf16x8(u);
#pragma unroll
            for (int nt = 0; nt < 4; ++nt) {
                bf16x8 bfr;
                ushort8 ub = wlds[(kc * 4 + nt) * 64 + l];
                __builtin_memcpy(&bfr, &ub, 16);
                acc[nt] = __builtin_amdgcn_mfma_f32_16x16x32_bf16(a, bfr, acc[nt], 0, 0, 0);
            }
        }
    }

    // epilogue: C/D layout col=lane&15, row=(lane>>4)*4+reg
    int colb = l & 15;
    int rquad = l >> 4;
    float dv[4], vv[4];
    int rowbase = r0 + rquad * 4;
#pragma unroll
    for (int rg = 0; rg < 4; ++rg) {
        int row = rowbase + rg;
        int rc = (row < N) ? row : (N - 1);
        dv[rg] = dinv[rc];
        vv[rg] = valv[rc];
    }
#pragma unroll
    for (int nt = 0; nt < 4; ++nt) {
        int col = nt * 16 + colb;
        float wcol = W1[col];                  // W1 row 0
#pragma unroll
        for (int rg = 0; rg < 4; ++rg) {
            int row = rowbase + rg;
            if (row < N)
                out[(size_t)row * 64 + col] = dv[rg] * (acc[nt][rg] + vv[rg] * wcol);
        }
    }
}

// ---------------- aggregation, 64 features: wave per node ----------------
template <int EPI>  // 0: leaky ; 1: leaky(t)+t
__global__ __launch_bounds__(256) void k_agg64(const float* __restrict__ hw, const int* __restrict__ rowoff,
                                               const int* __restrict__ colidx, const float* __restrict__ dinv,
                                               const float* __restrict__ bias, int N, float* __restrict__ out) {
    int w = threadIdx.x >> 6;
    int lane = threadIdx.x & 63;
    int v = blockIdx.x * 4 + w;
    if (v >= N) return;
    int beg = rowoff[v], end = rowoff[v + 1];
    float a0 = 0.f, a1 = 0.f, a2 = 0.f, a3 = 0.f;
    int i = beg;
    for (; i + 4 <= end; i += 4) {
        int u0 = colidx[i], u1 = colidx[i + 1], u2 = colidx[i + 2], u3 = colidx[i + 3];
        a0 += hw[(size_t)u0 * 64 + lane];
        a1 += hw[(size_t)u1 * 64 + lane];
        a2 += hw[(size_t)u2 * 64 + lane];
        a3 += hw[(size_t)u3 * 64 + lane];
    }
    for (; i < end; ++i) a0 += hw[(size_t)colidx[i] * 64 + lane];
    float t_ = dinv[v] * ((a0 + a1) + (a2 + a3)) + bias[lane];
    float r = (EPI == 0) ? (t_ >= 0.f ? t_ : 0.01f * t_) : (t_ >= 0.f ? 2.f * t_ : 1.01f * t_);
    out[(size_t)v * 64 + lane] = r;
}

// ---------------- aggregation, 32 features: half-wave per node ----------------
template <int EPI>
__global__ __launch_bounds__(256) void k_agg32(const float* __restrict__ hw, const int* __restrict__ rowoff,
                                               const int* __restrict__ colidx, const float* __restrict__ dinv,
                                               const float* __restrict__ bias, int N, float* __restrict__ out) {
    int sub = threadIdx.x >> 5;
    int lane = threadIdx.x & 31;
    int v = blockIdx.x * 8 + sub;
    if (v >= N) return;
    int beg = rowoff[v], end = rowoff[v + 1];
    float a0 = 0.f, a1 = 0.f, a2 = 0.f, a3 = 0.f;
    int i = beg;
    for (; i + 4 <= end; i += 4) {
        int u0 = colidx[i], u1 = colidx[i + 1], u2 = colidx[i + 2], u3 = colidx[i + 3];
        a0 += hw[(size_t)u0 * 32 + lane];
        a1 += hw[(size_t)u1 * 32 + lane];
        a2 += hw[(size_t)u2 * 32 + lane];
        a3 += hw[(size_t)u3 * 32 + lane];
    }
    for (; i < end; ++i) a0 += hw[(size_t)colidx[i] * 32 + lane];
    float t_ = dinv[v] * ((a0 + a1) + (a2 + a3)) + bias[lane];
    float r = (EPI == 0) ? (t_ >= 0.f ? t_ : 0.01f * t_) : (t_ >= 0.f ? 2.f * t_ : 1.01f * t_);
    out[(size_t)v * 32 + lane] = r;
}

// ---------------- small GEMM ----------------
template <int K, int C>
__global__ __launch_bounds__(256) void k_gemmS(const float* __restrict__ h, const float* __restrict__ W,
                                               const float* __restrict__ dinv, int N, float* __restrict__ out) {
    __shared__ float ws[K * C];
    for (int j = threadIdx.x; j < K * C; j += 256) ws[j] = W[j];
    __syncthreads();
    const int rpb = 256 / C;
    int lr = threadIdx.x / C;
    int col = threadIdx.x % C;
    int row = blockIdx.x * rpb + lr;
    if (row >= N) return;
    const float* hr = h + (size_t)row * K;
    float acc = 0.f;
#pragma unroll
    for (int k = 0; k < K; ++k) acc += hr[k] * ws[k * C + col];
    out[(size_t)row * C + col] = acc * dinv[row];
}

// ---------------- GEMM5 ----------------
__global__ __launch_bounds__(256) void k_gemm5(const float* __restrict__ h, const float* __restrict__ W5,
                                               const float* __restrict__ dinv, int N, float* __restrict__ out) {
    int sub = threadIdx.x >> 5;
    int lane = threadIdx.x & 31;
    int row = blockIdx.x * 8 + sub;
    if (row >= N) return;
    float p = h[(size_t)row * 32 + lane] * W5[lane];
#pragma unroll
    for (int o = 16; o > 0; o >>= 1) p += __shfl_down(p, o, 32);
    if (lane == 0) out[row] = p * dinv[row];
}

// ---------------- aggregation, 1 feature ----------------
__global__ void k_agg1f(const float* __restrict__ hw, const int* __restrict__ rowoff,
                        const int* __restrict__ colidx, const float* __restrict__ dinv,
                        const float* __restrict__ b5, int N, float* __restrict__ vvec) {
    int v = blockIdx.x * blockDim.x + threadIdx.x;
    if (v >= N) return;
    int beg = rowoff[v], end = rowoff[v + 1];
    float s = 0.f;
    for (int i = beg; i < end; ++i) s += hw[colidx[i]];
    float h = dinv[v] * s + b5[0];
    vvec[v] = h >= 0.f ? h : 0.01f * h;
}

// ---------------- fc1 partial ----------------
__global__ __launch_bounds__(128) void k_fc1(const float* __restrict__ vvec, const float* __restrict__ fc1W,
                                             int N, float* __restrict__ accum) {
    int o = threadIdx.x;
    int rpb = (N + gridDim.x - 1) / gridDim.x;
    int r0 = blockIdx.x * rpb;
    int r1 = r0 + rpb;
    if (r1 > N) r1 = N;
    float acc = 0.f;
    for (int r = r0; r < r1; ++r) acc += vvec[r] * fc1W[(size_t)r * 128 + o];
    atomicAdd(&accum[o], acc);
}

// ---------------- fc2 final ----------------
__global__ __launch_bounds__(128) void k_fc2(const float* __restrict__ accum, const float* __restrict__ fc1b,
                                             const float* __restrict__ fc2W, const float* __restrict__ fc2b,
                                             float* __restrict__ outp) {
    __shared__ float s1[128];
    int t = threadIdx.x;
    float h = accum[t] + fc1b[t];
    s1[t] = h > 0.f ? h : 0.f;
    __syncthreads();
    float acc = fc2b[t];
    for (int o = 0; o < 128; ++o) acc += s1[o] * fc2W[o * 128 + t];
    outp[t] = acc > 0.f ? acc : 0.f;
}

extern "C" void kernel_launch(void* const* d_in, const int* in_sizes, int n_in,
                              void* d_out, int out_size, void* d_ws, size_t ws_size,
                              hipStream_t stream) {
    const float* x = (const float*)d_in[0];
    const int* ei = (const int*)d_in[2];
    const float* emb = (const float*)d_in[3];
    const float* W1 = (const float*)d_in[4];
    const float* b1 = (const float*)d_in[5];
    const float* W2 = (const float*)d_in[6];
    const float* b2 = (const float*)d_in[7];
    const float* W3 = (const float*)d_in[8];
    const float* b3 = (const float*)d_in[9];
    const float* W4 = (const float*)d_in[10];
    const float* b4 = (const float*)d_in[11];
    const float* W5 = (const float*)d_in[12];
    const float* b5 = (const float*)d_in[13];
    const float* fc1W = (const float*)d_in[14];
    const float* fc1b = (const float*)d_in[15];
    const float* fc2W = (const float*)d_in[16];
    const float* fc2b = (const float*)d_in[17];

    int N = in_sizes[0] / FEATN;
    int E = in_sizes[2] / 2;
    int NNZ = E + N;
    int NBC = (N + CSZ - 1) / CSZ;      // coarse buckets of 256 nodes

    char* w = (char*)d_ws;
    auto alloc = [&](size_t bytes) {
        char* p = w;
        w += (bytes + 255) & ~(size_t)255;
        return p;
    };
    float* dinv   = (float*)alloc((size_t)N * 4);
    int*   rowoff = (int*)alloc((size_t)(N + 1) * 4);
    int*   colidx = (int*)alloc((size_t)NNZ * 4);
    float* valv   = (float*)alloc((size_t)N * 4);
    float* accum  = (float*)alloc(512);
    int*   flag   = (int*)alloc(256);
    int*   gtails = (int*)alloc((size_t)NBC * 4);
    int*   boff   = (int*)alloc((size_t)NBC * 4);
    unsigned int* bb = (unsigned int*)alloc((size_t)NBC * CAP2 * 4);
    unsigned short* Wf = (unsigned short*)alloc((size_t)KT_ALL * 4 * 64 * 8 * 2);
    float* bufA   = (float*)alloc((size_t)N * 64 * 4);
    float* bufB   = (float*)alloc((size_t)N * 64 * 4);
    float* vvec   = (float*)alloc((size_t)N * 4);

    int nb = (N + 255) / 256;

    k_detect<<<1, 256, 0, stream>>>(ei, flag);
    k_init<<<1, 256, 0, stream>>>(gtails, NBC, accum);
    k_p1<<<(E + EPB - 1) / EPB, 256, 0, stream>>>(ei, E, N, NBC, flag, gtails, bb);
    k_p1b<<<1, 256, 0, stream>>>(gtails, N, NBC, boff, rowoff + N);
    k_p2<<<NBC, 256, 0, stream>>>(bb, gtails, boff, N, rowoff, dinv, colidx);
    k_val<<<nb, 256, 0, stream>>>(x, emb, N, valv);
    k_prepW<<<(KT_ALL * 4 * 64 * 8 + 255) / 256, 256, 0, stream>>>(W1, Wf);

    k_gemm1m<<<(N + 63) / 64, 256, 0, stream>>>(x, Wf, W1, valv, dinv, N, bufA);
    k_agg64<0><<<(N + 3) / 4, 256, 0, stream>>>(bufA, rowoff, colidx, dinv, b1, N, bufB);

    k_gemmS<64, 32><<<(N + 7) / 8, 256, 0, stream>>>(bufB, W2, dinv, N, bufA);
    k_agg32<0><<<(N + 7) / 8, 256, 0, stream>>>(bufA, rowoff, colidx, dinv, b2, N, bufB);

    k_gemmS<32, 32><<<(N + 7) / 8, 256, 0, stream>>>(bufB, W3, dinv, N, bufA);
    k_agg32<1><<<(N + 7) / 8, 256, 0, stream>>>(bufA, rowoff, colidx, dinv, b3, N, bufB);

    k_gemmS<32, 32><<<(N + 7) / 8, 256, 0, stream>>>(bufB, W4, dinv, N, bufA);
    k_agg32<1><<<(N + 7) / 8, 256, 0, stream>>>(bufA, rowoff, colidx, dinv, b4, N, bufB);

    k_gemm5<<<(N + 7) / 8, 256, 0, stream>>>(bufB, W5, dinv, N, bufA);
    k_agg1f<<<nb, 256, 0, stream>>>(bufA, rowoff, colidx, dinv, b5, N, vvec);

    k_fc1<<<300, 128, 0, stream>>>(vvec, fc1W, N, accum);
    k_fc2<<<1, 128, 0, stream>>>(accum, fc1b, fc2W, fc2b, (float*)d_out);
}